// Round 1
// baseline (1979.743 us; speedup 1.0000x reference)
//
#include <hip/hip_runtime.h>

// GCN: 2-layer GraphConv, N=100000 nodes, E=1600000 edges, 128 -> 128 -> 40.
// Pipeline:
//   deg -> norms -> scatter1 (atomics, 128-wide) -> GEMM1 (fused dst_norm, bias, relu)
//   -> GEMM2 weight-first (fused src_norm) -> scatter2 (atomics, 40-wide) -> epilogue.
constexpr int NN  = 100000;
constexpr int NE  = 1600000;
constexpr int INF = 128;
constexpr int HIDD = 128;
constexpr int NC  = 40;

__global__ void deg_kernel(const int* __restrict__ src, const int* __restrict__ dst,
                           float* __restrict__ deg_out, float* __restrict__ deg_in) {
    int e = blockIdx.x * blockDim.x + threadIdx.x;
    if (e < NE) {
        unsafeAtomicAdd(&deg_out[src[e]], 1.0f);
        unsafeAtomicAdd(&deg_in[dst[e]], 1.0f);
    }
}

// in-place over [deg_out | deg_in] (2N floats): deg -> rsqrt(max(deg,1))
__global__ void norm_kernel(float* __restrict__ deg) {
    int i = blockIdx.x * blockDim.x + threadIdx.x;
    if (i < 2 * NN) deg[i] = rsqrtf(fmaxf(deg[i], 1.0f));
}

// one wave per edge: agg[dst] += x[src] * src_norm[src]   (128 floats, float2/lane)
__global__ void scatter1_kernel(const int* __restrict__ src, const int* __restrict__ dst,
                                const float* __restrict__ x, const float* __restrict__ src_norm,
                                float* __restrict__ agg) {
    int wave = (blockIdx.x * blockDim.x + threadIdx.x) >> 6;
    int lane = threadIdx.x & 63;
    if (wave >= NE) return;
    int s = src[wave];
    int d = dst[wave];
    float sn = src_norm[s];
    float2 v = ((const float2*)(x + (size_t)s * INF))[lane];
    float* ar = agg + (size_t)d * INF + lane * 2;
    unsafeAtomicAdd(ar,     v.x * sn);
    unsafeAtomicAdd(ar + 1, v.y * sn);
}

// GEMM1: h = relu((agg * dst_norm) @ W1 + b1), in place over agg.
// 256 threads, 32 rows/block (100000 = 3125*32 exactly). K tiled in 2 chunks of 64
// to keep static LDS under 64KB (W chunk 32KB + rows 16KB).
__global__ __launch_bounds__(256) void gemm1_kernel(float* __restrict__ agg,
                                                    const float* __restrict__ W1,
                                                    const float* __restrict__ b1,
                                                    const float* __restrict__ dst_norm) {
    __shared__ float Wl[64 * HIDD];   // k-chunk x 128 cols
    __shared__ float Rl[32 * INF];    // 32 rows x 128
    const int tid = threadIdx.x;
    const int r0 = blockIdx.x * 32;

    // load rows, scale by dst_norm
    {
        const float4* Ag = (const float4*)(agg + (size_t)r0 * INF);
        float4* Rs = (float4*)Rl;
#pragma unroll
        for (int i = 0; i < 4; ++i) {
            int j = tid + i * 256;        // vec idx, 32 vecs per row
            int row = j >> 5;
            float dn = dst_norm[r0 + row];
            float4 v = Ag[j];
            v.x *= dn; v.y *= dn; v.z *= dn; v.w *= dn;
            Rs[j] = v;
        }
    }

    const int cblk = tid & 31;  const int c0 = cblk * 4;
    const int rblk = tid >> 5;  // 0..7 -> rows rblk*4 .. +3
    float acc[4][4] = {};

    for (int kt = 0; kt < 2; ++kt) {
        __syncthreads();  // rows ready (kt=0) / prev chunk consumed (kt=1)
        {
            const float4* Wg = (const float4*)(W1 + kt * 64 * HIDD);
            float4* Ws = (float4*)Wl;
#pragma unroll
            for (int i = 0; i < 8; ++i) Ws[tid + i * 256] = Wg[tid + i * 256];
        }
        __syncthreads();
#pragma unroll 4
        for (int k = 0; k < 64; k += 4) {
            float4 rv[4];
#pragma unroll
            for (int r = 0; r < 4; ++r)
                rv[r] = *(const float4*)&Rl[(rblk * 4 + r) * INF + kt * 64 + k];
            float4 wv[4];
#pragma unroll
            for (int kk = 0; kk < 4; ++kk)
                wv[kk] = *(const float4*)&Wl[(k + kk) * HIDD + c0];
#pragma unroll
            for (int r = 0; r < 4; ++r) {
                float rr[4] = {rv[r].x, rv[r].y, rv[r].z, rv[r].w};
#pragma unroll
                for (int kk = 0; kk < 4; ++kk) {
                    acc[r][0] += rr[kk] * wv[kk].x;
                    acc[r][1] += rr[kk] * wv[kk].y;
                    acc[r][2] += rr[kk] * wv[kk].z;
                    acc[r][3] += rr[kk] * wv[kk].w;
                }
            }
        }
    }

    const float4 bb = *(const float4*)&b1[c0];
#pragma unroll
    for (int r = 0; r < 4; ++r) {
        int row = r0 + rblk * 4 + r;
        float4 o;
        o.x = fmaxf(acc[r][0] + bb.x, 0.0f);
        o.y = fmaxf(acc[r][1] + bb.y, 0.0f);
        o.z = fmaxf(acc[r][2] + bb.z, 0.0f);
        o.w = fmaxf(acc[r][3] + bb.w, 0.0f);
        *(float4*)&agg[(size_t)row * HIDD + c0] = o;
    }
}

// GEMM2 (weight-first): hw = (h @ W2) * src_norm.  320 threads, 64 rows/block.
__global__ __launch_bounds__(320) void gemm2_kernel(const float* __restrict__ h,
                                                    const float* __restrict__ W2,
                                                    const float* __restrict__ src_norm,
                                                    float* __restrict__ hw) {
    __shared__ float Wl[HIDD * NC];   // 128 x 40 = 20KB
    __shared__ float Rl[64 * HIDD];   // 32KB
    const int tid = threadIdx.x;
    const int r0 = blockIdx.x * 64;

    for (int i = tid; i < HIDD * NC; i += 320) Wl[i] = W2[i];
    {
        const float4* Hg = (const float4*)(h + (size_t)r0 * HIDD);
        float4* Rs = (float4*)Rl;
        for (int j = tid; j < 64 * HIDD / 4; j += 320) {
            int row = j >> 5;
            float4 v = make_float4(0.f, 0.f, 0.f, 0.f);
            if (r0 + row < NN) v = Hg[j];
            Rs[j] = v;
        }
    }
    __syncthreads();

    const int c  = tid % 40;
    const int rg = tid / 40;   // 0..7 -> rows rg*8 .. +7
    float acc[8] = {};
#pragma unroll 4
    for (int k = 0; k < HIDD; k += 4) {
        float w0 = Wl[(k + 0) * NC + c];
        float w1 = Wl[(k + 1) * NC + c];
        float w2 = Wl[(k + 2) * NC + c];
        float w3 = Wl[(k + 3) * NC + c];
#pragma unroll
        for (int r = 0; r < 8; ++r) {
            float4 rv = *(const float4*)&Rl[(rg * 8 + r) * HIDD + k];
            acc[r] += rv.x * w0 + rv.y * w1 + rv.z * w2 + rv.w * w3;
        }
    }
#pragma unroll
    for (int r = 0; r < 8; ++r) {
        int row = r0 + rg * 8 + r;
        if (row < NN) hw[(size_t)row * NC + c] = acc[r] * src_norm[row];
    }
}

// out[dst] += hw[src], one thread per (edge, feat)
__global__ void scatter2_kernel(const int* __restrict__ src, const int* __restrict__ dst,
                                const float* __restrict__ hw, float* __restrict__ out) {
    unsigned int gid = blockIdx.x * blockDim.x + threadIdx.x;
    if (gid >= (unsigned int)NE * NC) return;
    unsigned int e = gid / NC;
    unsigned int f = gid - e * NC;
    int s = src[e], d = dst[e];
    unsafeAtomicAdd(&out[(size_t)d * NC + f], hw[(size_t)s * NC + f]);
}

// out = out * dst_norm + b2   (float4 over N*40; 10 vecs per row)
__global__ void final_kernel(float* __restrict__ out, const float* __restrict__ dst_norm,
                             const float* __restrict__ b2) {
    int j = blockIdx.x * blockDim.x + threadIdx.x;
    if (j >= NN * 10) return;
    int row = j / 10;
    int fc = (j - row * 10) * 4;
    float dn = dst_norm[row];
    float4 v = ((float4*)out)[j];
    const float4 bb = *(const float4*)&b2[fc];
    v.x = v.x * dn + bb.x;
    v.y = v.y * dn + bb.y;
    v.z = v.z * dn + bb.z;
    v.w = v.w * dn + bb.w;
    ((float4*)out)[j] = v;
}

extern "C" void kernel_launch(void* const* d_in, const int* in_sizes, int n_in,
                              void* d_out, int out_size, void* d_ws, size_t ws_size,
                              hipStream_t stream) {
    const float* x   = (const float*)d_in[0];
    const float* W1  = (const float*)d_in[1];
    const float* b1  = (const float*)d_in[2];
    const float* W2  = (const float*)d_in[3];
    const float* b2  = (const float*)d_in[4];
    const int*   src = (const int*)d_in[5];
    const int*   dst = (const int*)d_in[6];
    float* out = (float*)d_out;

    // workspace layout (floats): deg_out[N] | deg_in[N] | agg[N*128] | hw[N*40]
    float* deg_out = (float*)d_ws;
    float* deg_in  = deg_out + NN;
    float* agg     = deg_in + NN;
    float* hw      = agg + (size_t)NN * INF;

    // zero: degrees + agg (contiguous), and d_out (poisoned each call)
    hipMemsetAsync(deg_out, 0, (2 * (size_t)NN + (size_t)NN * INF) * sizeof(float), stream);
    hipMemsetAsync(out, 0, (size_t)NN * NC * sizeof(float), stream);

    deg_kernel<<<(NE + 255) / 256, 256, 0, stream>>>(src, dst, deg_out, deg_in);
    norm_kernel<<<(2 * NN + 255) / 256, 256, 0, stream>>>(deg_out);
    // src_norm = deg_out, dst_norm = deg_in (in place)
    scatter1_kernel<<<NE / 4, 256, 0, stream>>>(src, dst, x, deg_out, agg);
    gemm1_kernel<<<NN / 32, 256, 0, stream>>>(agg, W1, b1, deg_in);
    gemm2_kernel<<<(NN + 63) / 64, 320, 0, stream>>>(agg, W2, deg_out, hw);
    scatter2_kernel<<<((unsigned)NE * NC + 255) / 256, 256, 0, stream>>>(src, dst, hw, out);
    final_kernel<<<(NN * 10 + 255) / 256, 256, 0, stream>>>(out, deg_in, b2);
}

// Round 2
// 700.629 us; speedup vs baseline: 2.8257x; 2.8257x over previous
//
#include <hip/hip_runtime.h>

// GCN: 2-layer GraphConv, N=100000, E=1600000, 128 -> 128 -> 40 (fp32).
// Round 2: CSR-by-dst build per launch + gather-based aggregation (no feature atomics).
//   deg(int hist) -> scan(3 kernels) -> norm(in-place) -> bucket(esrc) ->
//   gather1 -> GEMM1(fused dst_norm,bias,relu) -> GEMM2 weight-first (fused src_norm)
//   -> gather2 (fused *dst_norm + b2 -> out)
constexpr int NN   = 100000;
constexpr int NE   = 1600000;
constexpr int INF  = 128;
constexpr int HIDD = 128;
constexpr int NC   = 40;
constexpr int NB   = (NN + 255) / 256;   // 391 scan blocks

__global__ void deg_kernel(const int* __restrict__ src, const int* __restrict__ dst,
                           unsigned int* __restrict__ deg_out, unsigned int* __restrict__ deg_in) {
    int e = blockIdx.x * blockDim.x + threadIdx.x;
    if (e < NE) {
        atomicAdd(&deg_out[src[e]], 1u);
        atomicAdd(&deg_in[dst[e]], 1u);
    }
}

// per-block sums of deg_in
__global__ __launch_bounds__(256) void scan_part_kernel(const unsigned int* __restrict__ deg_in,
                                                        unsigned int* __restrict__ bsum) {
    __shared__ unsigned int s[256];
    int tid = threadIdx.x;
    int i = blockIdx.x * 256 + tid;
    s[tid] = (i < NN) ? deg_in[i] : 0u;
    __syncthreads();
    for (int off = 128; off > 0; off >>= 1) {
        if (tid < off) s[tid] += s[tid + off];
        __syncthreads();
    }
    if (tid == 0) bsum[blockIdx.x] = s[0];
}

// single-block exclusive scan of NB block sums (in place)
__global__ __launch_bounds__(512) void scan_bsum_kernel(unsigned int* __restrict__ bsum) {
    __shared__ unsigned int s[512];
    int tid = threadIdx.x;
    unsigned int v = (tid < NB) ? bsum[tid] : 0u;
    s[tid] = v;
    __syncthreads();
    for (int off = 1; off < 512; off <<= 1) {
        unsigned int t = (tid >= off) ? s[tid - off] : 0u;
        __syncthreads();
        s[tid] += t;
        __syncthreads();
    }
    if (tid < NB) bsum[tid] = s[tid] - v;   // exclusive
}

// in-block exclusive scan + block offset -> row_ptr, cursor
__global__ __launch_bounds__(256) void scan_final_kernel(const unsigned int* __restrict__ deg_in,
                                                         const unsigned int* __restrict__ bsum,
                                                         int* __restrict__ row_ptr,
                                                         int* __restrict__ cursor) {
    __shared__ unsigned int s[256];
    int tid = threadIdx.x;
    int i = blockIdx.x * 256 + tid;
    unsigned int v = (i < NN) ? deg_in[i] : 0u;
    s[tid] = v;
    __syncthreads();
    for (int off = 1; off < 256; off <<= 1) {
        unsigned int t = (tid >= off) ? s[tid - off] : 0u;
        __syncthreads();
        s[tid] += t;
        __syncthreads();
    }
    unsigned int excl = s[tid] - v + bsum[blockIdx.x];
    if (i < NN) {
        row_ptr[i] = (int)excl;
        cursor[i]  = (int)excl;
    }
    if (i == NN - 1) row_ptr[NN] = (int)(excl + v);   // == NE
}

// in-place: uint degree -> float rsqrt(max(deg,1)) over [deg_out|deg_in]
__global__ void norm_kernel(unsigned int* __restrict__ deg) {
    int i = blockIdx.x * blockDim.x + threadIdx.x;
    if (i < 2 * NN) {
        float d = (float)deg[i];
        ((float*)deg)[i] = rsqrtf(fmaxf(d, 1.0f));
    }
}

// bucket edges by dst: esrc[pos] = src[e]
__global__ void bucket_kernel(const int* __restrict__ src, const int* __restrict__ dst,
                              int* __restrict__ cursor, int* __restrict__ esrc) {
    int e = blockIdx.x * blockDim.x + threadIdx.x;
    if (e < NE) {
        int pos = atomicAdd(&cursor[dst[e]], 1);
        esrc[pos] = src[e];
    }
}

// one wave per node: agg[node] = sum_{e in CSR[node]} x[esrc[e]] * src_norm[esrc[e]]
__global__ __launch_bounds__(256) void gather1_kernel(const int* __restrict__ row_ptr,
                                                      const int* __restrict__ esrc,
                                                      const float* __restrict__ x,
                                                      const float* __restrict__ src_norm,
                                                      float* __restrict__ agg) {
    int node = (blockIdx.x * blockDim.x + threadIdx.x) >> 6;
    int lane = threadIdx.x & 63;
    if (node >= NN) return;
    int beg = __builtin_amdgcn_readfirstlane(row_ptr[node]);
    int end = __builtin_amdgcn_readfirstlane(row_ptr[node + 1]);
    float2 acc = make_float2(0.f, 0.f);
    for (int e = beg; e < end; ++e) {
        int s = esrc[e];                                   // wave-uniform
        float sn = src_norm[s];
        float2 v = ((const float2*)(x + (size_t)s * INF))[lane];
        acc.x += v.x * sn;
        acc.y += v.y * sn;
    }
    ((float2*)(agg + (size_t)node * INF))[lane] = acc;
}

// GEMM1: h = relu((agg * dst_norm) @ W1 + b1), in place over agg.
__global__ __launch_bounds__(256) void gemm1_kernel(float* __restrict__ agg,
                                                    const float* __restrict__ W1,
                                                    const float* __restrict__ b1,
                                                    const float* __restrict__ dst_norm) {
    __shared__ float Wl[64 * HIDD];
    __shared__ float Rl[32 * INF];
    const int tid = threadIdx.x;
    const int r0 = blockIdx.x * 32;

    {
        const float4* Ag = (const float4*)(agg + (size_t)r0 * INF);
        float4* Rs = (float4*)Rl;
#pragma unroll
        for (int i = 0; i < 4; ++i) {
            int j = tid + i * 256;
            int row = j >> 5;
            float dn = dst_norm[r0 + row];
            float4 v = Ag[j];
            v.x *= dn; v.y *= dn; v.z *= dn; v.w *= dn;
            Rs[j] = v;
        }
    }

    const int cblk = tid & 31;  const int c0 = cblk * 4;
    const int rblk = tid >> 5;
    float acc[4][4] = {};

    for (int kt = 0; kt < 2; ++kt) {
        __syncthreads();
        {
            const float4* Wg = (const float4*)(W1 + kt * 64 * HIDD);
            float4* Ws = (float4*)Wl;
#pragma unroll
            for (int i = 0; i < 8; ++i) Ws[tid + i * 256] = Wg[tid + i * 256];
        }
        __syncthreads();
#pragma unroll 4
        for (int k = 0; k < 64; k += 4) {
            float4 rv[4];
#pragma unroll
            for (int r = 0; r < 4; ++r)
                rv[r] = *(const float4*)&Rl[(rblk * 4 + r) * INF + kt * 64 + k];
            float4 wv[4];
#pragma unroll
            for (int kk = 0; kk < 4; ++kk)
                wv[kk] = *(const float4*)&Wl[(k + kk) * HIDD + c0];
#pragma unroll
            for (int r = 0; r < 4; ++r) {
                float rr[4] = {rv[r].x, rv[r].y, rv[r].z, rv[r].w};
#pragma unroll
                for (int kk = 0; kk < 4; ++kk) {
                    acc[r][0] += rr[kk] * wv[kk].x;
                    acc[r][1] += rr[kk] * wv[kk].y;
                    acc[r][2] += rr[kk] * wv[kk].z;
                    acc[r][3] += rr[kk] * wv[kk].w;
                }
            }
        }
    }

    const float4 bb = *(const float4*)&b1[c0];
#pragma unroll
    for (int r = 0; r < 4; ++r) {
        int row = r0 + rblk * 4 + r;
        float4 o;
        o.x = fmaxf(acc[r][0] + bb.x, 0.0f);
        o.y = fmaxf(acc[r][1] + bb.y, 0.0f);
        o.z = fmaxf(acc[r][2] + bb.z, 0.0f);
        o.w = fmaxf(acc[r][3] + bb.w, 0.0f);
        *(float4*)&agg[(size_t)row * HIDD + c0] = o;
    }
}

// GEMM2 (weight-first): hw = (h @ W2) * src_norm.
__global__ __launch_bounds__(320) void gemm2_kernel(const float* __restrict__ h,
                                                    const float* __restrict__ W2,
                                                    const float* __restrict__ src_norm,
                                                    float* __restrict__ hw) {
    __shared__ float Wl[HIDD * NC];
    __shared__ float Rl[64 * HIDD];
    const int tid = threadIdx.x;
    const int r0 = blockIdx.x * 64;

    for (int i = tid; i < HIDD * NC; i += 320) Wl[i] = W2[i];
    {
        const float4* Hg = (const float4*)(h + (size_t)r0 * HIDD);
        float4* Rs = (float4*)Rl;
        for (int j = tid; j < 64 * HIDD / 4; j += 320) {
            int row = j >> 5;
            float4 v = make_float4(0.f, 0.f, 0.f, 0.f);
            if (r0 + row < NN) v = Hg[j];
            Rs[j] = v;
        }
    }
    __syncthreads();

    const int c  = tid % 40;
    const int rg = tid / 40;
    float acc[8] = {};
#pragma unroll 4
    for (int k = 0; k < HIDD; k += 4) {
        float w0 = Wl[(k + 0) * NC + c];
        float w1 = Wl[(k + 1) * NC + c];
        float w2 = Wl[(k + 2) * NC + c];
        float w3 = Wl[(k + 3) * NC + c];
#pragma unroll
        for (int r = 0; r < 8; ++r) {
            float4 rv = *(const float4*)&Rl[(rg * 8 + r) * HIDD + k];
            acc[r] += rv.x * w0 + rv.y * w1 + rv.z * w2 + rv.w * w3;
        }
    }
#pragma unroll
    for (int r = 0; r < 8; ++r) {
        int row = r0 + rg * 8 + r;
        if (row < NN) hw[(size_t)row * NC + c] = acc[r] * src_norm[row];
    }
}

// one wave per node, lanes 0..39: out[node] = (sum hw[esrc[e]]) * dst_norm[node] + b2
__global__ __launch_bounds__(256) void gather2_kernel(const int* __restrict__ row_ptr,
                                                      const int* __restrict__ esrc,
                                                      const float* __restrict__ hw,
                                                      const float* __restrict__ dst_norm,
                                                      const float* __restrict__ b2,
                                                      float* __restrict__ out) {
    int node = (blockIdx.x * blockDim.x + threadIdx.x) >> 6;
    int lane = threadIdx.x & 63;
    if (node >= NN || lane >= NC) return;
    int beg = __builtin_amdgcn_readfirstlane(row_ptr[node]);
    int end = __builtin_amdgcn_readfirstlane(row_ptr[node + 1]);
    float acc = 0.f;
    for (int e = beg; e < end; ++e) {
        int s = esrc[e];
        acc += hw[(size_t)s * NC + lane];
    }
    out[(size_t)node * NC + lane] = acc * dst_norm[node] + b2[lane];
}

extern "C" void kernel_launch(void* const* d_in, const int* in_sizes, int n_in,
                              void* d_out, int out_size, void* d_ws, size_t ws_size,
                              hipStream_t stream) {
    const float* x   = (const float*)d_in[0];
    const float* W1  = (const float*)d_in[1];
    const float* b1  = (const float*)d_in[2];
    const float* W2  = (const float*)d_in[3];
    const float* b2  = (const float*)d_in[4];
    const int*   src = (const int*)d_in[5];
    const int*   dst = (const int*)d_in[6];
    float* out = (float*)d_out;

    // workspace layout (4B units):
    // deg_out[N] | deg_in[N] | row_ptr[N+1] | cursor[N] | bsum[512] | esrc[NE] | pad | agg[N*128] | hw[N*40]
    unsigned int* deg_out = (unsigned int*)d_ws;
    unsigned int* deg_in  = deg_out + NN;
    int* row_ptr = (int*)(deg_in + NN);
    int* cursor  = row_ptr + NN + 1;
    unsigned int* bsum = (unsigned int*)(cursor + NN);
    int* esrc = (int*)(bsum + 512);
    size_t ofs = (size_t)(2 * NN) + (NN + 1) + NN + 512 + NE;
    ofs = (ofs + 3) & ~(size_t)3;                 // 16B align
    float* agg = (float*)d_ws + ofs;
    float* hw  = agg + (size_t)NN * INF;

    hipMemsetAsync(deg_out, 0, 2 * (size_t)NN * sizeof(int), stream);

    deg_kernel<<<(NE + 255) / 256, 256, 0, stream>>>(src, dst, deg_out, deg_in);
    scan_part_kernel<<<NB, 256, 0, stream>>>(deg_in, bsum);
    scan_bsum_kernel<<<1, 512, 0, stream>>>(bsum);
    scan_final_kernel<<<NB, 256, 0, stream>>>(deg_in, bsum, row_ptr, cursor);
    norm_kernel<<<(2 * NN + 255) / 256, 256, 0, stream>>>(deg_out);
    // src_norm = (float*)deg_out, dst_norm = (float*)deg_in (converted in place)
    bucket_kernel<<<(NE + 255) / 256, 256, 0, stream>>>(src, dst, cursor, esrc);
    gather1_kernel<<<(NN * 64 + 255) / 256, 256, 0, stream>>>(row_ptr, esrc, x,
                                                              (const float*)deg_out, agg);
    gemm1_kernel<<<NN / 32, 256, 0, stream>>>(agg, W1, b1, (const float*)deg_in);
    gemm2_kernel<<<(NN + 63) / 64, 320, 0, stream>>>(agg, W2, (const float*)deg_out, hw);
    gather2_kernel<<<(NN * 64 + 255) / 256, 256, 0, stream>>>(row_ptr, esrc, hw,
                                                              (const float*)deg_in, b2, out);
}

// Round 3
// 658.534 us; speedup vs baseline: 3.0063x; 1.0639x over previous
//
#include <hip/hip_runtime.h>

// GCN: 2-layer GraphConv, N=100000, E=1600000, 128 -> 128 -> 40 (fp32).
// Round 3: MLP-optimized gathers (float4 half-wave, 8 edges in flight),
// norm fused into scan_final. Pipeline:
//   memset -> deg -> scan_part -> scan_bsum -> scan_final(+norms) -> bucket ->
//   gather1 -> GEMM1(fused dst_norm,bias,relu) -> GEMM2 weight-first (fused src_norm)
//   -> gather2 (fused *dst_norm + b2 -> out)
constexpr int NN   = 100000;
constexpr int NE   = 1600000;
constexpr int INF  = 128;
constexpr int HIDD = 128;
constexpr int NC   = 40;
constexpr int NB   = (NN + 255) / 256;   // 391 scan blocks

__global__ void deg_kernel(const int* __restrict__ src, const int* __restrict__ dst,
                           unsigned int* __restrict__ deg_out, unsigned int* __restrict__ deg_in) {
    int e = blockIdx.x * blockDim.x + threadIdx.x;
    if (e < NE) {
        atomicAdd(&deg_out[src[e]], 1u);
        atomicAdd(&deg_in[dst[e]], 1u);
    }
}

// per-block sums of deg_in
__global__ __launch_bounds__(256) void scan_part_kernel(const unsigned int* __restrict__ deg_in,
                                                        unsigned int* __restrict__ bsum) {
    __shared__ unsigned int s[256];
    int tid = threadIdx.x;
    int i = blockIdx.x * 256 + tid;
    s[tid] = (i < NN) ? deg_in[i] : 0u;
    __syncthreads();
    for (int off = 128; off > 0; off >>= 1) {
        if (tid < off) s[tid] += s[tid + off];
        __syncthreads();
    }
    if (tid == 0) bsum[blockIdx.x] = s[0];
}

// single-block exclusive scan of NB block sums (in place)
__global__ __launch_bounds__(512) void scan_bsum_kernel(unsigned int* __restrict__ bsum) {
    __shared__ unsigned int s[512];
    int tid = threadIdx.x;
    unsigned int v = (tid < NB) ? bsum[tid] : 0u;
    s[tid] = v;
    __syncthreads();
    for (int off = 1; off < 512; off <<= 1) {
        unsigned int t = (tid >= off) ? s[tid - off] : 0u;
        __syncthreads();
        s[tid] += t;
        __syncthreads();
    }
    if (tid < NB) bsum[tid] = s[tid] - v;   // exclusive
}

// in-block exclusive scan + block offset -> row_ptr, cursor.
// Also converts BOTH degree arrays to rsqrt norms in place (fused norm_kernel).
__global__ __launch_bounds__(256) void scan_final_kernel(unsigned int* __restrict__ deg_in,
                                                         unsigned int* __restrict__ deg_out,
                                                         const unsigned int* __restrict__ bsum,
                                                         int* __restrict__ row_ptr,
                                                         int* __restrict__ cursor) {
    __shared__ unsigned int s[256];
    int tid = threadIdx.x;
    int i = blockIdx.x * 256 + tid;
    unsigned int v = (i < NN) ? deg_in[i] : 0u;
    s[tid] = v;
    __syncthreads();
    for (int off = 1; off < 256; off <<= 1) {
        unsigned int t = (tid >= off) ? s[tid - off] : 0u;
        __syncthreads();
        s[tid] += t;
        __syncthreads();
    }
    unsigned int excl = s[tid] - v + bsum[blockIdx.x];
    if (i < NN) {
        row_ptr[i] = (int)excl;
        cursor[i]  = (int)excl;
        ((float*)deg_in)[i]  = rsqrtf(fmaxf((float)v, 1.0f));           // dst_norm
        ((float*)deg_out)[i] = rsqrtf(fmaxf((float)deg_out[i], 1.0f));  // src_norm
    }
    if (i == NN - 1) row_ptr[NN] = (int)(excl + v);   // == NE
}

// bucket edges by dst: esrc[pos] = src[e]
__global__ void bucket_kernel(const int* __restrict__ src, const int* __restrict__ dst,
                              int* __restrict__ cursor, int* __restrict__ esrc) {
    int e = blockIdx.x * blockDim.x + threadIdx.x;
    if (e < NE) {
        int pos = atomicAdd(&cursor[dst[e]], 1);
        esrc[pos] = src[e];
    }
}

// one wave per node: agg[node] = sum_{e in CSR[node]} x[esrc[e]] * src_norm[esrc[e]]
// half-waves: lanes 0-31 take even edge of a pair, 32-63 the odd; float4/lane.
// Main loop keeps 4 row-loads (8 edges) in flight for memory-level parallelism.
__global__ __launch_bounds__(256) void gather1_kernel(const int* __restrict__ row_ptr,
                                                      const int* __restrict__ esrc,
                                                      const float* __restrict__ x,
                                                      const float* __restrict__ src_norm,
                                                      float* __restrict__ agg) {
    int node = (blockIdx.x * blockDim.x + threadIdx.x) >> 6;
    int lane = threadIdx.x & 63;
    if (node >= NN) return;
    int beg = __builtin_amdgcn_readfirstlane(row_ptr[node]);
    int end = __builtin_amdgcn_readfirstlane(row_ptr[node + 1]);
    const int half = lane >> 5;
    const int l32  = lane & 31;
    float4 acc = make_float4(0.f, 0.f, 0.f, 0.f);
    int e = beg;
    for (; e + 8 <= end; e += 8) {
        int s0 = esrc[e + 0 + half];
        int s1 = esrc[e + 2 + half];
        int s2 = esrc[e + 4 + half];
        int s3 = esrc[e + 6 + half];
        float n0 = src_norm[s0], n1 = src_norm[s1], n2 = src_norm[s2], n3 = src_norm[s3];
        float4 v0 = ((const float4*)(x + (size_t)s0 * INF))[l32];
        float4 v1 = ((const float4*)(x + (size_t)s1 * INF))[l32];
        float4 v2 = ((const float4*)(x + (size_t)s2 * INF))[l32];
        float4 v3 = ((const float4*)(x + (size_t)s3 * INF))[l32];
        acc.x += v0.x * n0; acc.y += v0.y * n0; acc.z += v0.z * n0; acc.w += v0.w * n0;
        acc.x += v1.x * n1; acc.y += v1.y * n1; acc.z += v1.z * n1; acc.w += v1.w * n1;
        acc.x += v2.x * n2; acc.y += v2.y * n2; acc.z += v2.z * n2; acc.w += v2.w * n2;
        acc.x += v3.x * n3; acc.y += v3.y * n3; acc.z += v3.z * n3; acc.w += v3.w * n3;
    }
    for (; e + 2 <= end; e += 2) {
        int s0 = esrc[e + half];
        float n0 = src_norm[s0];
        float4 v0 = ((const float4*)(x + (size_t)s0 * INF))[l32];
        acc.x += v0.x * n0; acc.y += v0.y * n0; acc.z += v0.z * n0; acc.w += v0.w * n0;
    }
    if (e < end && half == 0) {
        int s0 = esrc[e];
        float n0 = src_norm[s0];
        float4 v0 = ((const float4*)(x + (size_t)s0 * INF))[l32];
        acc.x += v0.x * n0; acc.y += v0.y * n0; acc.z += v0.z * n0; acc.w += v0.w * n0;
    }
    // combine halves: feature chunk l32 lives in lanes l32 and l32+32
    acc.x += __shfl_down(acc.x, 32);
    acc.y += __shfl_down(acc.y, 32);
    acc.z += __shfl_down(acc.z, 32);
    acc.w += __shfl_down(acc.w, 32);
    if (half == 0) ((float4*)(agg + (size_t)node * INF))[l32] = acc;
}

// GEMM1: h = relu((agg * dst_norm) @ W1 + b1), in place over agg.
__global__ __launch_bounds__(256) void gemm1_kernel(float* __restrict__ agg,
                                                    const float* __restrict__ W1,
                                                    const float* __restrict__ b1,
                                                    const float* __restrict__ dst_norm) {
    __shared__ float Wl[64 * HIDD];
    __shared__ float Rl[32 * INF];
    const int tid = threadIdx.x;
    const int r0 = blockIdx.x * 32;

    {
        const float4* Ag = (const float4*)(agg + (size_t)r0 * INF);
        float4* Rs = (float4*)Rl;
#pragma unroll
        for (int i = 0; i < 4; ++i) {
            int j = tid + i * 256;
            int row = j >> 5;
            float dn = dst_norm[r0 + row];
            float4 v = Ag[j];
            v.x *= dn; v.y *= dn; v.z *= dn; v.w *= dn;
            Rs[j] = v;
        }
    }

    const int cblk = tid & 31;  const int c0 = cblk * 4;
    const int rblk = tid >> 5;
    float acc[4][4] = {};

    for (int kt = 0; kt < 2; ++kt) {
        __syncthreads();
        {
            const float4* Wg = (const float4*)(W1 + kt * 64 * HIDD);
            float4* Ws = (float4*)Wl;
#pragma unroll
            for (int i = 0; i < 8; ++i) Ws[tid + i * 256] = Wg[tid + i * 256];
        }
        __syncthreads();
#pragma unroll 4
        for (int k = 0; k < 64; k += 4) {
            float4 rv[4];
#pragma unroll
            for (int r = 0; r < 4; ++r)
                rv[r] = *(const float4*)&Rl[(rblk * 4 + r) * INF + kt * 64 + k];
            float4 wv[4];
#pragma unroll
            for (int kk = 0; kk < 4; ++kk)
                wv[kk] = *(const float4*)&Wl[(k + kk) * HIDD + c0];
#pragma unroll
            for (int r = 0; r < 4; ++r) {
                float rr[4] = {rv[r].x, rv[r].y, rv[r].z, rv[r].w};
#pragma unroll
                for (int kk = 0; kk < 4; ++kk) {
                    acc[r][0] += rr[kk] * wv[kk].x;
                    acc[r][1] += rr[kk] * wv[kk].y;
                    acc[r][2] += rr[kk] * wv[kk].z;
                    acc[r][3] += rr[kk] * wv[kk].w;
                }
            }
        }
    }

    const float4 bb = *(const float4*)&b1[c0];
#pragma unroll
    for (int r = 0; r < 4; ++r) {
        int row = r0 + rblk * 4 + r;
        float4 o;
        o.x = fmaxf(acc[r][0] + bb.x, 0.0f);
        o.y = fmaxf(acc[r][1] + bb.y, 0.0f);
        o.z = fmaxf(acc[r][2] + bb.z, 0.0f);
        o.w = fmaxf(acc[r][3] + bb.w, 0.0f);
        *(float4*)&agg[(size_t)row * HIDD + c0] = o;
    }
}

// GEMM2 (weight-first): hw = (h @ W2) * src_norm.
__global__ __launch_bounds__(320) void gemm2_kernel(const float* __restrict__ h,
                                                    const float* __restrict__ W2,
                                                    const float* __restrict__ src_norm,
                                                    float* __restrict__ hw) {
    __shared__ float Wl[HIDD * NC];
    __shared__ float Rl[64 * HIDD];
    const int tid = threadIdx.x;
    const int r0 = blockIdx.x * 64;

    for (int i = tid; i < HIDD * NC; i += 320) Wl[i] = W2[i];
    {
        const float4* Hg = (const float4*)(h + (size_t)r0 * HIDD);
        float4* Rs = (float4*)Rl;
        for (int j = tid; j < 64 * HIDD / 4; j += 320) {
            int row = j >> 5;
            float4 v = make_float4(0.f, 0.f, 0.f, 0.f);
            if (r0 + row < NN) v = Hg[j];
            Rs[j] = v;
        }
    }
    __syncthreads();

    const int c  = tid % 40;
    const int rg = tid / 40;
    float acc[8] = {};
#pragma unroll 4
    for (int k = 0; k < HIDD; k += 4) {
        float w0 = Wl[(k + 0) * NC + c];
        float w1 = Wl[(k + 1) * NC + c];
        float w2 = Wl[(k + 2) * NC + c];
        float w3 = Wl[(k + 3) * NC + c];
#pragma unroll
        for (int r = 0; r < 8; ++r) {
            float4 rv = *(const float4*)&Rl[(rg * 8 + r) * HIDD + k];
            acc[r] += rv.x * w0 + rv.y * w1 + rv.z * w2 + rv.w * w3;
        }
    }
#pragma unroll
    for (int r = 0; r < 8; ++r) {
        int row = r0 + rg * 8 + r;
        if (row < NN) hw[(size_t)row * NC + c] = acc[r] * src_norm[row];
    }
}

// one wave per node, lanes 0..39: out[node] = (sum hw[esrc[e]]) * dst_norm[node] + b2
// 4 edges in flight per iteration.
__global__ __launch_bounds__(256) void gather2_kernel(const int* __restrict__ row_ptr,
                                                      const int* __restrict__ esrc,
                                                      const float* __restrict__ hw,
                                                      const float* __restrict__ dst_norm,
                                                      const float* __restrict__ b2,
                                                      float* __restrict__ out) {
    int node = (blockIdx.x * blockDim.x + threadIdx.x) >> 6;
    int lane = threadIdx.x & 63;
    if (node >= NN || lane >= NC) return;
    int beg = __builtin_amdgcn_readfirstlane(row_ptr[node]);
    int end = __builtin_amdgcn_readfirstlane(row_ptr[node + 1]);
    float acc = 0.f;
    int e = beg;
    for (; e + 4 <= end; e += 4) {
        int s0 = esrc[e + 0];
        int s1 = esrc[e + 1];
        int s2 = esrc[e + 2];
        int s3 = esrc[e + 3];
        float a0 = hw[(size_t)s0 * NC + lane];
        float a1 = hw[(size_t)s1 * NC + lane];
        float a2 = hw[(size_t)s2 * NC + lane];
        float a3 = hw[(size_t)s3 * NC + lane];
        acc += a0 + a1 + a2 + a3;
    }
    for (; e < end; ++e) {
        acc += hw[(size_t)esrc[e] * NC + lane];
    }
    out[(size_t)node * NC + lane] = acc * dst_norm[node] + b2[lane];
}

extern "C" void kernel_launch(void* const* d_in, const int* in_sizes, int n_in,
                              void* d_out, int out_size, void* d_ws, size_t ws_size,
                              hipStream_t stream) {
    const float* x   = (const float*)d_in[0];
    const float* W1  = (const float*)d_in[1];
    const float* b1  = (const float*)d_in[2];
    const float* W2  = (const float*)d_in[3];
    const float* b2  = (const float*)d_in[4];
    const int*   src = (const int*)d_in[5];
    const int*   dst = (const int*)d_in[6];
    float* out = (float*)d_out;

    // workspace layout (4B units):
    // deg_out[N] | deg_in[N] | row_ptr[N+1] | cursor[N] | bsum[512] | esrc[NE] | pad | agg[N*128] | hw[N*40]
    unsigned int* deg_out = (unsigned int*)d_ws;
    unsigned int* deg_in  = deg_out + NN;
    int* row_ptr = (int*)(deg_in + NN);
    int* cursor  = row_ptr + NN + 1;
    unsigned int* bsum = (unsigned int*)(cursor + NN);
    int* esrc = (int*)(bsum + 512);
    size_t ofs = (size_t)(2 * NN) + (NN + 1) + NN + 512 + NE;
    ofs = (ofs + 3) & ~(size_t)3;                 // 16B align
    float* agg = (float*)d_ws + ofs;
    float* hw  = agg + (size_t)NN * INF;

    hipMemsetAsync(deg_out, 0, 2 * (size_t)NN * sizeof(int), stream);

    deg_kernel<<<(NE + 255) / 256, 256, 0, stream>>>(src, dst, deg_out, deg_in);
    scan_part_kernel<<<NB, 256, 0, stream>>>(deg_in, bsum);
    scan_bsum_kernel<<<1, 512, 0, stream>>>(bsum);
    scan_final_kernel<<<NB, 256, 0, stream>>>(deg_in, deg_out, bsum, row_ptr, cursor);
    // src_norm = (float*)deg_out, dst_norm = (float*)deg_in (converted in place)
    bucket_kernel<<<(NE + 255) / 256, 256, 0, stream>>>(src, dst, cursor, esrc);
    gather1_kernel<<<(NN * 64 + 255) / 256, 256, 0, stream>>>(row_ptr, esrc, x,
                                                              (const float*)deg_out, agg);
    gemm1_kernel<<<NN / 32, 256, 0, stream>>>(agg, W1, b1, (const float*)deg_in);
    gemm2_kernel<<<(NN + 63) / 64, 320, 0, stream>>>(agg, W2, (const float*)deg_out, hw);
    gather2_kernel<<<(NN * 64 + 255) / 256, 256, 0, stream>>>(row_ptr, esrc, hw,
                                                              (const float*)deg_in, b2, out);
}

// Round 5
// 509.995 us; speedup vs baseline: 3.8819x; 1.2913x over previous
//
#include <hip/hip_runtime.h>

// GCN: 2-layer GraphConv, N=100000, E=1600000, 128 -> 128 -> 40 (fp32).
// Round 5: Round-4 counting-sort CSR build with the partition dump-index fix
// (bucket_cursor already starts at bucket_base; gadj must NOT add bucket_base again).
//   memset -> hist (coarse dst-bucket + src out-degree) -> bucket_scan ->
//   partition (LDS-staged, coalesced dump to d_out scratch) ->
//   pass2 (per-bucket local hist/scan/scatter in LDS -> row_ptr, norms, esrc) ->
//   gather1 -> GEMM1(fused dst_norm,bias,relu) -> GEMM2 weight-first (fused src_norm)
//   -> gather2 (fused *dst_norm + b2 -> out)
constexpr int NN   = 100000;
constexpr int NE   = 1600000;
constexpr int INF  = 128;
constexpr int HIDD = 128;
constexpr int NC   = 40;

constexpr int BKSH = 9;                        // 512 nodes per coarse bucket
constexpr int NBK  = (NN + 511) / 512;         // 196 buckets
constexpr int EPB  = 8192;                     // edges per partition block
constexpr int PBLK = (NE + EPB - 1) / EPB;     // 196
constexpr int CAP  = 14336;                    // pass2 LDS esrc capacity (56 KB)

// coarse dst histogram (LDS-aggregated) + src out-degree histogram
__global__ __launch_bounds__(256) void hist_kernel(const int* __restrict__ src,
                                                   const int* __restrict__ dst,
                                                   unsigned int* __restrict__ deg_out,
                                                   unsigned int* __restrict__ bucket_cnt) {
    __shared__ unsigned int hc[NBK];
    const int tid = threadIdx.x;
    for (int i = tid; i < NBK; i += 256) hc[i] = 0u;
    __syncthreads();
    int gid = blockIdx.x * 256 + tid;
    int stride = gridDim.x * 256;
    for (int e = gid; e < NE; e += stride) {
        atomicAdd(&deg_out[src[e]], 1u);
        atomicAdd(&hc[dst[e] >> BKSH], 1u);
    }
    __syncthreads();
    for (int i = tid; i < NBK; i += 256)
        if (hc[i]) atomicAdd(&bucket_cnt[i], hc[i]);
}

// exclusive scan of 196 bucket counts -> bucket_base, init bucket_cursor
__global__ __launch_bounds__(256) void bucket_scan_kernel(const unsigned int* __restrict__ bucket_cnt,
                                                          int* __restrict__ bucket_base,
                                                          int* __restrict__ bucket_cursor) {
    __shared__ int s[256];
    const int tid = threadIdx.x;
    int v = (tid < NBK) ? (int)bucket_cnt[tid] : 0;
    s[tid] = v;
    __syncthreads();
    for (int off = 1; off < 256; off <<= 1) {
        int t = (tid >= off) ? s[tid - off] : 0;
        __syncthreads();
        s[tid] += t;
        __syncthreads();
    }
    int excl = s[tid] - v;
    if (tid < NBK) { bucket_base[tid] = excl; bucket_cursor[tid] = excl; }
    if (tid == NBK - 1) bucket_base[NBK] = excl + v;   // == NE
}

// partition edges into coarse buckets, LDS-staged so global writes are coalesced runs.
// record = src | (dst_local << 17)   (src < 2^17, dst_local < 512)
__global__ __launch_bounds__(256) void partition_kernel(const int* __restrict__ src,
                                                        const int* __restrict__ dst,
                                                        int* __restrict__ bucket_cursor,
                                                        int* __restrict__ eparts) {
    __shared__ int cnt[NBK];
    __shared__ int sc[256];
    __shared__ int gadj[NBK];
    __shared__ int cur[NBK];
    __shared__ int stage[EPB];
    __shared__ unsigned char bid[EPB];
    const int tid = threadIdx.x;
    const int e0 = blockIdx.x * EPB;
    const int total = min(EPB, NE - e0);

    for (int i = tid; i < NBK; i += 256) cnt[i] = 0;
    __syncthreads();
    // phase A: count per bucket
    for (int i = tid; i < total; i += 256)
        atomicAdd(&cnt[dst[e0 + i] >> BKSH], 1);
    __syncthreads();
    // exclusive scan of cnt
    int v = (tid < NBK) ? cnt[tid] : 0;
    sc[tid] = v;
    __syncthreads();
    for (int off = 1; off < 256; off <<= 1) {
        int t = (tid >= off) ? sc[tid - off] : 0;
        __syncthreads();
        sc[tid] += t;
        __syncthreads();
    }
    if (tid < NBK) {
        int excl = sc[tid] - v;
        cur[tid] = excl;
        // bucket_cursor starts at bucket_base, so g is ALREADY absolute.
        int g = (v > 0) ? atomicAdd(&bucket_cursor[tid], v) : 0;
        gadj[tid] = g - excl;   // FIX: do not add bucket_base again
    }
    __syncthreads();
    // phase B: re-read edges, stage grouped by bucket
    for (int i = tid; i < total; i += 256) {
        int s = src[e0 + i];
        int d = dst[e0 + i];
        int b = d >> BKSH;
        int dl = d - (b << BKSH);
        int off = atomicAdd(&cur[b], 1);
        stage[off] = s | (dl << 17);
        bid[off] = (unsigned char)b;
    }
    __syncthreads();
    // dump: consecutive j within a bucket-run -> consecutive global addresses
    for (int j = tid; j < total; j += 256) {
        int b = bid[j];
        eparts[gadj[b] + j] = stage[j];
    }
}

// per-bucket fine CSR: local hist + scan + LDS scatter -> row_ptr, dst_norm,
// src_norm (in-place convert), esrc (coalesced dump).
__global__ __launch_bounds__(512) void pass2_kernel(const int* __restrict__ eparts,
                                                    const int* __restrict__ bucket_base,
                                                    int* __restrict__ row_ptr,
                                                    int* __restrict__ esrc,
                                                    unsigned int* __restrict__ deg_out,
                                                    float* __restrict__ dstn) {
    __shared__ int hist[512];
    __shared__ int cur[512];
    __shared__ int lesrc[CAP];
    const int tid = threadIdx.x;
    const int b = blockIdx.x;
    const int base = bucket_base[b];
    const int cnt = bucket_base[b + 1] - base;
    const int n0 = b << BKSH;
    const int nloc = min(512, NN - n0);

    hist[tid] = 0;
    __syncthreads();
    for (int j = tid; j < cnt; j += 512)
        atomicAdd(&hist[eparts[base + j] >> 17], 1);
    __syncthreads();
    int myc = hist[tid];
    // inclusive scan of hist in place
    for (int off = 1; off < 512; off <<= 1) {
        int t = (tid >= off) ? hist[tid - off] : 0;
        __syncthreads();
        hist[tid] += t;
        __syncthreads();
    }
    int excl = hist[tid] - myc;
    cur[tid] = excl;
    if (tid < nloc) {
        int g = n0 + tid;
        row_ptr[g] = base + excl;
        dstn[g] = rsqrtf(fmaxf((float)myc, 1.0f));                    // dst_norm
        float sd = (float)deg_out[g];
        ((float*)deg_out)[g] = rsqrtf(fmaxf(sd, 1.0f));               // src_norm in place
    }
    if (b == NBK - 1 && tid == 0) row_ptr[NN] = NE;
    __syncthreads();
    if (cnt <= CAP) {
        for (int j = tid; j < cnt; j += 512) {
            int rec = eparts[base + j];
            int pos = atomicAdd(&cur[rec >> 17], 1);
            lesrc[pos] = rec & 0x1FFFF;
        }
        __syncthreads();
        for (int j = tid; j < cnt; j += 512) esrc[base + j] = lesrc[j];
    } else {
        // safe fallback (statistically unreachable): direct global scatter
        for (int j = tid; j < cnt; j += 512) {
            int rec = eparts[base + j];
            int pos = atomicAdd(&cur[rec >> 17], 1);
            esrc[base + pos] = rec & 0x1FFFF;
        }
    }
}

// one wave per node: agg[node] = sum_{e in CSR[node]} x[esrc[e]] * src_norm[esrc[e]]
// half-waves: lanes 0-31 even edge, 32-63 odd; float4/lane; 8 edges in flight.
__global__ __launch_bounds__(256) void gather1_kernel(const int* __restrict__ row_ptr,
                                                      const int* __restrict__ esrc,
                                                      const float* __restrict__ x,
                                                      const float* __restrict__ src_norm,
                                                      float* __restrict__ agg) {
    int node = (blockIdx.x * blockDim.x + threadIdx.x) >> 6;
    int lane = threadIdx.x & 63;
    if (node >= NN) return;
    int beg = __builtin_amdgcn_readfirstlane(row_ptr[node]);
    int end = __builtin_amdgcn_readfirstlane(row_ptr[node + 1]);
    const int half = lane >> 5;
    const int l32  = lane & 31;
    float4 acc = make_float4(0.f, 0.f, 0.f, 0.f);
    int e = beg;
    for (; e + 8 <= end; e += 8) {
        int s0 = esrc[e + 0 + half];
        int s1 = esrc[e + 2 + half];
        int s2 = esrc[e + 4 + half];
        int s3 = esrc[e + 6 + half];
        float n0 = src_norm[s0], n1 = src_norm[s1], n2 = src_norm[s2], n3 = src_norm[s3];
        float4 v0 = ((const float4*)(x + (size_t)s0 * INF))[l32];
        float4 v1 = ((const float4*)(x + (size_t)s1 * INF))[l32];
        float4 v2 = ((const float4*)(x + (size_t)s2 * INF))[l32];
        float4 v3 = ((const float4*)(x + (size_t)s3 * INF))[l32];
        acc.x += v0.x * n0; acc.y += v0.y * n0; acc.z += v0.z * n0; acc.w += v0.w * n0;
        acc.x += v1.x * n1; acc.y += v1.y * n1; acc.z += v1.z * n1; acc.w += v1.w * n1;
        acc.x += v2.x * n2; acc.y += v2.y * n2; acc.z += v2.z * n2; acc.w += v2.w * n2;
        acc.x += v3.x * n3; acc.y += v3.y * n3; acc.z += v3.z * n3; acc.w += v3.w * n3;
    }
    for (; e + 2 <= end; e += 2) {
        int s0 = esrc[e + half];
        float n0 = src_norm[s0];
        float4 v0 = ((const float4*)(x + (size_t)s0 * INF))[l32];
        acc.x += v0.x * n0; acc.y += v0.y * n0; acc.z += v0.z * n0; acc.w += v0.w * n0;
    }
    if (e < end && half == 0) {
        int s0 = esrc[e];
        float n0 = src_norm[s0];
        float4 v0 = ((const float4*)(x + (size_t)s0 * INF))[l32];
        acc.x += v0.x * n0; acc.y += v0.y * n0; acc.z += v0.z * n0; acc.w += v0.w * n0;
    }
    acc.x += __shfl_down(acc.x, 32);
    acc.y += __shfl_down(acc.y, 32);
    acc.z += __shfl_down(acc.z, 32);
    acc.w += __shfl_down(acc.w, 32);
    if (half == 0) ((float4*)(agg + (size_t)node * INF))[l32] = acc;
}

// GEMM1: h = relu((agg * dst_norm) @ W1 + b1), in place over agg.
__global__ __launch_bounds__(256) void gemm1_kernel(float* __restrict__ agg,
                                                    const float* __restrict__ W1,
                                                    const float* __restrict__ b1,
                                                    const float* __restrict__ dst_norm) {
    __shared__ float Wl[64 * HIDD];
    __shared__ float Rl[32 * INF];
    const int tid = threadIdx.x;
    const int r0 = blockIdx.x * 32;

    {
        const float4* Ag = (const float4*)(agg + (size_t)r0 * INF);
        float4* Rs = (float4*)Rl;
#pragma unroll
        for (int i = 0; i < 4; ++i) {
            int j = tid + i * 256;
            int row = j >> 5;
            float dn = dst_norm[r0 + row];
            float4 v = Ag[j];
            v.x *= dn; v.y *= dn; v.z *= dn; v.w *= dn;
            Rs[j] = v;
        }
    }

    const int cblk = tid & 31;  const int c0 = cblk * 4;
    const int rblk = tid >> 5;
    float acc[4][4] = {};

    for (int kt = 0; kt < 2; ++kt) {
        __syncthreads();
        {
            const float4* Wg = (const float4*)(W1 + kt * 64 * HIDD);
            float4* Ws = (float4*)Wl;
#pragma unroll
            for (int i = 0; i < 8; ++i) Ws[tid + i * 256] = Wg[tid + i * 256];
        }
        __syncthreads();
#pragma unroll 4
        for (int k = 0; k < 64; k += 4) {
            float4 rv[4];
#pragma unroll
            for (int r = 0; r < 4; ++r)
                rv[r] = *(const float4*)&Rl[(rblk * 4 + r) * INF + kt * 64 + k];
            float4 wv[4];
#pragma unroll
            for (int kk = 0; kk < 4; ++kk)
                wv[kk] = *(const float4*)&Wl[(k + kk) * HIDD + c0];
#pragma unroll
            for (int r = 0; r < 4; ++r) {
                float rr[4] = {rv[r].x, rv[r].y, rv[r].z, rv[r].w};
#pragma unroll
                for (int kk = 0; kk < 4; ++kk) {
                    acc[r][0] += rr[kk] * wv[kk].x;
                    acc[r][1] += rr[kk] * wv[kk].y;
                    acc[r][2] += rr[kk] * wv[kk].z;
                    acc[r][3] += rr[kk] * wv[kk].w;
                }
            }
        }
    }

    const float4 bb = *(const float4*)&b1[c0];
#pragma unroll
    for (int r = 0; r < 4; ++r) {
        int row = r0 + rblk * 4 + r;
        float4 o;
        o.x = fmaxf(acc[r][0] + bb.x, 0.0f);
        o.y = fmaxf(acc[r][1] + bb.y, 0.0f);
        o.z = fmaxf(acc[r][2] + bb.z, 0.0f);
        o.w = fmaxf(acc[r][3] + bb.w, 0.0f);
        *(float4*)&agg[(size_t)row * HIDD + c0] = o;
    }
}

// GEMM2 (weight-first): hw = (h @ W2) * src_norm.
__global__ __launch_bounds__(320) void gemm2_kernel(const float* __restrict__ h,
                                                    const float* __restrict__ W2,
                                                    const float* __restrict__ src_norm,
                                                    float* __restrict__ hw) {
    __shared__ float Wl[HIDD * NC];
    __shared__ float Rl[64 * HIDD];
    const int tid = threadIdx.x;
    const int r0 = blockIdx.x * 64;

    for (int i = tid; i < HIDD * NC; i += 320) Wl[i] = W2[i];
    {
        const float4* Hg = (const float4*)(h + (size_t)r0 * HIDD);
        float4* Rs = (float4*)Rl;
        for (int j = tid; j < 64 * HIDD / 4; j += 320) {
            int row = j >> 5;
            float4 v = make_float4(0.f, 0.f, 0.f, 0.f);
            if (r0 + row < NN) v = Hg[j];
            Rs[j] = v;
        }
    }
    __syncthreads();

    const int c  = tid % 40;
    const int rg = tid / 40;
    float acc[8] = {};
#pragma unroll 4
    for (int k = 0; k < HIDD; k += 4) {
        float w0 = Wl[(k + 0) * NC + c];
        float w1 = Wl[(k + 1) * NC + c];
        float w2 = Wl[(k + 2) * NC + c];
        float w3 = Wl[(k + 3) * NC + c];
#pragma unroll
        for (int r = 0; r < 8; ++r) {
            float4 rv = *(const float4*)&Rl[(rg * 8 + r) * HIDD + k];
            acc[r] += rv.x * w0 + rv.y * w1 + rv.z * w2 + rv.w * w3;
        }
    }
#pragma unroll
    for (int r = 0; r < 8; ++r) {
        int row = r0 + rg * 8 + r;
        if (row < NN) hw[(size_t)row * NC + c] = acc[r] * src_norm[row];
    }
}

// one wave per node, lanes 0..39: out[node] = (sum hw[esrc[e]]) * dst_norm[node] + b2
__global__ __launch_bounds__(256) void gather2_kernel(const int* __restrict__ row_ptr,
                                                      const int* __restrict__ esrc,
                                                      const float* __restrict__ hw,
                                                      const float* __restrict__ dst_norm,
                                                      const float* __restrict__ b2,
                                                      float* __restrict__ out) {
    int node = (blockIdx.x * blockDim.x + threadIdx.x) >> 6;
    int lane = threadIdx.x & 63;
    if (node >= NN || lane >= NC) return;
    int beg = __builtin_amdgcn_readfirstlane(row_ptr[node]);
    int end = __builtin_amdgcn_readfirstlane(row_ptr[node + 1]);
    float acc = 0.f;
    int e = beg;
    for (; e + 4 <= end; e += 4) {
        int s0 = esrc[e + 0];
        int s1 = esrc[e + 1];
        int s2 = esrc[e + 2];
        int s3 = esrc[e + 3];
        float a0 = hw[(size_t)s0 * NC + lane];
        float a1 = hw[(size_t)s1 * NC + lane];
        float a2 = hw[(size_t)s2 * NC + lane];
        float a3 = hw[(size_t)s3 * NC + lane];
        acc += a0 + a1 + a2 + a3;
    }
    for (; e < end; ++e) {
        acc += hw[(size_t)esrc[e] * NC + lane];
    }
    out[(size_t)node * NC + lane] = acc * dst_norm[node] + b2[lane];
}

extern "C" void kernel_launch(void* const* d_in, const int* in_sizes, int n_in,
                              void* d_out, int out_size, void* d_ws, size_t ws_size,
                              hipStream_t stream) {
    const float* x   = (const float*)d_in[0];
    const float* W1  = (const float*)d_in[1];
    const float* b1  = (const float*)d_in[2];
    const float* W2  = (const float*)d_in[3];
    const float* b2  = (const float*)d_in[4];
    const int*   src = (const int*)d_in[5];
    const int*   dst = (const int*)d_in[6];
    float* out = (float*)d_out;

    // workspace (4B units):
    // deg_out[NN] | bucket_cnt[256] | bucket_base[256] | bucket_cursor[256] |
    // row_ptr[NN+1] | dstn[NN] | esrc[NE] | pad | agg[NN*128] | hw[NN*40]
    unsigned int* deg_out      = (unsigned int*)d_ws;
    unsigned int* bucket_cnt   = deg_out + NN;
    int* bucket_base   = (int*)(bucket_cnt + 256);
    int* bucket_cursor = bucket_base + 256;
    int* row_ptr = bucket_cursor + 256;
    float* dstn  = (float*)(row_ptr + NN + 1);
    int* esrc    = (int*)(dstn + NN);
    size_t ofs = (size_t)NN + 768 + (NN + 1) + NN + NE;
    ofs = (ofs + 3) & ~(size_t)3;                 // 16B align
    float* agg = (float*)d_ws + ofs;
    float* hw  = agg + (size_t)NN * INF;

    // eparts scratch lives in d_out (6.4 MB of 16 MB) — dead before gather2 writes
    int* eparts = (int*)d_out;

    hipMemsetAsync(deg_out, 0, ((size_t)NN + 256) * sizeof(int), stream);

    hist_kernel<<<391, 256, 0, stream>>>(src, dst, deg_out, bucket_cnt);
    bucket_scan_kernel<<<1, 256, 0, stream>>>(bucket_cnt, bucket_base, bucket_cursor);
    partition_kernel<<<PBLK, 256, 0, stream>>>(src, dst, bucket_cursor, eparts);
    pass2_kernel<<<NBK, 512, 0, stream>>>(eparts, bucket_base, row_ptr, esrc, deg_out, dstn);
    // src_norm = (float*)deg_out, dst_norm = dstn (written by pass2)
    gather1_kernel<<<(NN * 64 + 255) / 256, 256, 0, stream>>>(row_ptr, esrc, x,
                                                              (const float*)deg_out, agg);
    gemm1_kernel<<<NN / 32, 256, 0, stream>>>(agg, W1, b1, dstn);
    gemm2_kernel<<<(NN + 63) / 64, 320, 0, stream>>>(agg, W2, (const float*)deg_out, hw);
    gather2_kernel<<<(NN * 64 + 255) / 256, 256, 0, stream>>>(row_ptr, esrc, hw,
                                                              dstn, b2, out);
}

// Round 6
// 483.147 us; speedup vs baseline: 4.0976x; 1.0556x over previous
//
#include <hip/hip_runtime.h>

// GCN: 2-layer GraphConv, N=100000, E=1600000, 128 -> 128 -> 40 (fp32).
// Round 6: bf16 payload compression for the two gathers (accumulate fp32):
//   convert (x->bf16 xh) -> hist -> bucket_scan -> partition -> pass2 ->
//   gather1 (bf16 rows, 16 edges in flight) -> GEMM1 (fp32, fused dst_norm,bias,relu)
//   -> GEMM2 weight-first (stores bf16 hw) -> gather2 (bf16 rows, fused epilogue)
constexpr int NN   = 100000;
constexpr int NE   = 1600000;
constexpr int INF  = 128;
constexpr int HIDD = 128;
constexpr int NC   = 40;

constexpr int BKSH = 9;                        // 512 nodes per coarse bucket
constexpr int NBK  = (NN + 511) / 512;         // 196 buckets
constexpr int EPB  = 8192;                     // edges per partition block
constexpr int PBLK = (NE + EPB - 1) / EPB;     // 196
constexpr int CAP  = 14336;                    // pass2 LDS esrc capacity (56 KB)

__device__ __forceinline__ float bflo(unsigned int u) { return __uint_as_float(u << 16); }
__device__ __forceinline__ float bfhi(unsigned int u) { return __uint_as_float(u & 0xffff0000u); }
__device__ __forceinline__ unsigned short f2bf(float f) {          // RNE
    unsigned int u = __float_as_uint(f);
    return (unsigned short)((u + 0x7fffu + ((u >> 16) & 1u)) >> 16);
}
__device__ __forceinline__ unsigned int pack2(float a, float b) {
    return (unsigned int)f2bf(a) | ((unsigned int)f2bf(b) << 16);
}

// x (fp32, N*128) -> xh (bf16). 8 floats per thread.
__global__ __launch_bounds__(256) void convert_kernel(const float* __restrict__ x,
                                                      unsigned short* __restrict__ xh) {
    int j = blockIdx.x * 256 + threadIdx.x;          // uint4 index, N*128/8 = 1.6M
    if (j >= NN * INF / 8) return;
    float4 v0 = ((const float4*)x)[2 * j];
    float4 v1 = ((const float4*)x)[2 * j + 1];
    uint4 o;
    o.x = pack2(v0.x, v0.y);
    o.y = pack2(v0.z, v0.w);
    o.z = pack2(v1.x, v1.y);
    o.w = pack2(v1.z, v1.w);
    ((uint4*)xh)[j] = o;
}

// coarse dst histogram (LDS-aggregated) + src out-degree histogram
__global__ __launch_bounds__(256) void hist_kernel(const int* __restrict__ src,
                                                   const int* __restrict__ dst,
                                                   unsigned int* __restrict__ deg_out,
                                                   unsigned int* __restrict__ bucket_cnt) {
    __shared__ unsigned int hc[NBK];
    const int tid = threadIdx.x;
    for (int i = tid; i < NBK; i += 256) hc[i] = 0u;
    __syncthreads();
    int gid = blockIdx.x * 256 + tid;
    int stride = gridDim.x * 256;
    for (int e = gid; e < NE; e += stride) {
        atomicAdd(&deg_out[src[e]], 1u);
        atomicAdd(&hc[dst[e] >> BKSH], 1u);
    }
    __syncthreads();
    for (int i = tid; i < NBK; i += 256)
        if (hc[i]) atomicAdd(&bucket_cnt[i], hc[i]);
}

// exclusive scan of 196 bucket counts -> bucket_base, init bucket_cursor
__global__ __launch_bounds__(256) void bucket_scan_kernel(const unsigned int* __restrict__ bucket_cnt,
                                                          int* __restrict__ bucket_base,
                                                          int* __restrict__ bucket_cursor) {
    __shared__ int s[256];
    const int tid = threadIdx.x;
    int v = (tid < NBK) ? (int)bucket_cnt[tid] : 0;
    s[tid] = v;
    __syncthreads();
    for (int off = 1; off < 256; off <<= 1) {
        int t = (tid >= off) ? s[tid - off] : 0;
        __syncthreads();
        s[tid] += t;
        __syncthreads();
    }
    int excl = s[tid] - v;
    if (tid < NBK) { bucket_base[tid] = excl; bucket_cursor[tid] = excl; }
    if (tid == NBK - 1) bucket_base[NBK] = excl + v;   // == NE
}

// partition edges into coarse buckets, LDS-staged so global writes are coalesced runs.
// record = src | (dst_local << 17)   (src < 2^17, dst_local < 512)
__global__ __launch_bounds__(256) void partition_kernel(const int* __restrict__ src,
                                                        const int* __restrict__ dst,
                                                        int* __restrict__ bucket_cursor,
                                                        int* __restrict__ eparts) {
    __shared__ int cnt[NBK];
    __shared__ int sc[256];
    __shared__ int gadj[NBK];
    __shared__ int cur[NBK];
    __shared__ int stage[EPB];
    __shared__ unsigned char bid[EPB];
    const int tid = threadIdx.x;
    const int e0 = blockIdx.x * EPB;
    const int total = min(EPB, NE - e0);

    for (int i = tid; i < NBK; i += 256) cnt[i] = 0;
    __syncthreads();
    for (int i = tid; i < total; i += 256)
        atomicAdd(&cnt[dst[e0 + i] >> BKSH], 1);
    __syncthreads();
    int v = (tid < NBK) ? cnt[tid] : 0;
    sc[tid] = v;
    __syncthreads();
    for (int off = 1; off < 256; off <<= 1) {
        int t = (tid >= off) ? sc[tid - off] : 0;
        __syncthreads();
        sc[tid] += t;
        __syncthreads();
    }
    if (tid < NBK) {
        int excl = sc[tid] - v;
        cur[tid] = excl;
        // bucket_cursor starts at bucket_base, so g is ALREADY absolute.
        int g = (v > 0) ? atomicAdd(&bucket_cursor[tid], v) : 0;
        gadj[tid] = g - excl;
    }
    __syncthreads();
    for (int i = tid; i < total; i += 256) {
        int s = src[e0 + i];
        int d = dst[e0 + i];
        int b = d >> BKSH;
        int dl = d - (b << BKSH);
        int off = atomicAdd(&cur[b], 1);
        stage[off] = s | (dl << 17);
        bid[off] = (unsigned char)b;
    }
    __syncthreads();
    for (int j = tid; j < total; j += 256) {
        int b = bid[j];
        eparts[gadj[b] + j] = stage[j];
    }
}

// per-bucket fine CSR: local hist + scan + LDS scatter -> row_ptr, dst_norm,
// src_norm (in-place convert), esrc (coalesced dump).
__global__ __launch_bounds__(512) void pass2_kernel(const int* __restrict__ eparts,
                                                    const int* __restrict__ bucket_base,
                                                    int* __restrict__ row_ptr,
                                                    int* __restrict__ esrc,
                                                    unsigned int* __restrict__ deg_out,
                                                    float* __restrict__ dstn) {
    __shared__ int hist[512];
    __shared__ int cur[512];
    __shared__ int lesrc[CAP];
    const int tid = threadIdx.x;
    const int b = blockIdx.x;
    const int base = bucket_base[b];
    const int cnt = bucket_base[b + 1] - base;
    const int n0 = b << BKSH;
    const int nloc = min(512, NN - n0);

    hist[tid] = 0;
    __syncthreads();
    for (int j = tid; j < cnt; j += 512)
        atomicAdd(&hist[eparts[base + j] >> 17], 1);
    __syncthreads();
    int myc = hist[tid];
    for (int off = 1; off < 512; off <<= 1) {
        int t = (tid >= off) ? hist[tid - off] : 0;
        __syncthreads();
        hist[tid] += t;
        __syncthreads();
    }
    int excl = hist[tid] - myc;
    cur[tid] = excl;
    if (tid < nloc) {
        int g = n0 + tid;
        row_ptr[g] = base + excl;
        dstn[g] = rsqrtf(fmaxf((float)myc, 1.0f));                    // dst_norm
        float sd = (float)deg_out[g];
        ((float*)deg_out)[g] = rsqrtf(fmaxf(sd, 1.0f));               // src_norm in place
    }
    if (b == NBK - 1 && tid == 0) row_ptr[NN] = NE;
    __syncthreads();
    if (cnt <= CAP) {
        for (int j = tid; j < cnt; j += 512) {
            int rec = eparts[base + j];
            int pos = atomicAdd(&cur[rec >> 17], 1);
            lesrc[pos] = rec & 0x1FFFF;
        }
        __syncthreads();
        for (int j = tid; j < cnt; j += 512) esrc[base + j] = lesrc[j];
    } else {
        for (int j = tid; j < cnt; j += 512) {
            int rec = eparts[base + j];
            int pos = atomicAdd(&cur[rec >> 17], 1);
            esrc[base + pos] = rec & 0x1FFFF;
        }
    }
}

// one wave per node: agg[node] = sum x_bf16[esrc[e]] * src_norm[esrc[e]]  (fp32 acc)
// half-waves: lanes 0-31 even edge of pair, 32-63 odd; uint2 (4 bf16)/lane;
// 16 edges (8 row loads per half-lane) in flight.
__global__ __launch_bounds__(256) void gather1_kernel(const int* __restrict__ row_ptr,
                                                      const int* __restrict__ esrc,
                                                      const unsigned short* __restrict__ xh,
                                                      const float* __restrict__ src_norm,
                                                      float* __restrict__ agg) {
    int node = (blockIdx.x * blockDim.x + threadIdx.x) >> 6;
    int lane = threadIdx.x & 63;
    if (node >= NN) return;
    int beg = __builtin_amdgcn_readfirstlane(row_ptr[node]);
    int end = __builtin_amdgcn_readfirstlane(row_ptr[node + 1]);
    const int half = lane >> 5;
    const int l32  = lane & 31;
    float4 acc = make_float4(0.f, 0.f, 0.f, 0.f);
    int e = beg;
    for (; e + 16 <= end; e += 16) {
        int s0 = esrc[e + 0 + half];
        int s1 = esrc[e + 2 + half];
        int s2 = esrc[e + 4 + half];
        int s3 = esrc[e + 6 + half];
        int s4 = esrc[e + 8 + half];
        int s5 = esrc[e + 10 + half];
        int s6 = esrc[e + 12 + half];
        int s7 = esrc[e + 14 + half];
        float n0 = src_norm[s0], n1 = src_norm[s1], n2 = src_norm[s2], n3 = src_norm[s3];
        float n4 = src_norm[s4], n5 = src_norm[s5], n6 = src_norm[s6], n7 = src_norm[s7];
        uint2 u0 = ((const uint2*)(xh + (size_t)s0 * INF))[l32];
        uint2 u1 = ((const uint2*)(xh + (size_t)s1 * INF))[l32];
        uint2 u2 = ((const uint2*)(xh + (size_t)s2 * INF))[l32];
        uint2 u3 = ((const uint2*)(xh + (size_t)s3 * INF))[l32];
        uint2 u4 = ((const uint2*)(xh + (size_t)s4 * INF))[l32];
        uint2 u5 = ((const uint2*)(xh + (size_t)s5 * INF))[l32];
        uint2 u6 = ((const uint2*)(xh + (size_t)s6 * INF))[l32];
        uint2 u7 = ((const uint2*)(xh + (size_t)s7 * INF))[l32];
        acc.x += bflo(u0.x) * n0; acc.y += bfhi(u0.x) * n0; acc.z += bflo(u0.y) * n0; acc.w += bfhi(u0.y) * n0;
        acc.x += bflo(u1.x) * n1; acc.y += bfhi(u1.x) * n1; acc.z += bflo(u1.y) * n1; acc.w += bfhi(u1.y) * n1;
        acc.x += bflo(u2.x) * n2; acc.y += bfhi(u2.x) * n2; acc.z += bflo(u2.y) * n2; acc.w += bfhi(u2.y) * n2;
        acc.x += bflo(u3.x) * n3; acc.y += bfhi(u3.x) * n3; acc.z += bflo(u3.y) * n3; acc.w += bfhi(u3.y) * n3;
        acc.x += bflo(u4.x) * n4; acc.y += bfhi(u4.x) * n4; acc.z += bflo(u4.y) * n4; acc.w += bfhi(u4.y) * n4;
        acc.x += bflo(u5.x) * n5; acc.y += bfhi(u5.x) * n5; acc.z += bflo(u5.y) * n5; acc.w += bfhi(u5.y) * n5;
        acc.x += bflo(u6.x) * n6; acc.y += bfhi(u6.x) * n6; acc.z += bflo(u6.y) * n6; acc.w += bfhi(u6.y) * n6;
        acc.x += bflo(u7.x) * n7; acc.y += bfhi(u7.x) * n7; acc.z += bflo(u7.y) * n7; acc.w += bfhi(u7.y) * n7;
    }
    for (; e + 2 <= end; e += 2) {
        int s0 = esrc[e + half];
        float n0 = src_norm[s0];
        uint2 u0 = ((const uint2*)(xh + (size_t)s0 * INF))[l32];
        acc.x += bflo(u0.x) * n0; acc.y += bfhi(u0.x) * n0; acc.z += bflo(u0.y) * n0; acc.w += bfhi(u0.y) * n0;
    }
    if (e < end && half == 0) {
        int s0 = esrc[e];
        float n0 = src_norm[s0];
        uint2 u0 = ((const uint2*)(xh + (size_t)s0 * INF))[l32];
        acc.x += bflo(u0.x) * n0; acc.y += bfhi(u0.x) * n0; acc.z += bflo(u0.y) * n0; acc.w += bfhi(u0.y) * n0;
    }
    acc.x += __shfl_down(acc.x, 32);
    acc.y += __shfl_down(acc.y, 32);
    acc.z += __shfl_down(acc.z, 32);
    acc.w += __shfl_down(acc.w, 32);
    if (half == 0) ((float4*)(agg + (size_t)node * INF))[l32] = acc;
}

// GEMM1: h = relu((agg * dst_norm) @ W1 + b1), in place over agg (fp32).
__global__ __launch_bounds__(256) void gemm1_kernel(float* __restrict__ agg,
                                                    const float* __restrict__ W1,
                                                    const float* __restrict__ b1,
                                                    const float* __restrict__ dst_norm) {
    __shared__ float Wl[64 * HIDD];
    __shared__ float Rl[32 * INF];
    const int tid = threadIdx.x;
    const int r0 = blockIdx.x * 32;

    {
        const float4* Ag = (const float4*)(agg + (size_t)r0 * INF);
        float4* Rs = (float4*)Rl;
#pragma unroll
        for (int i = 0; i < 4; ++i) {
            int j = tid + i * 256;
            int row = j >> 5;
            float dn = dst_norm[r0 + row];
            float4 v = Ag[j];
            v.x *= dn; v.y *= dn; v.z *= dn; v.w *= dn;
            Rs[j] = v;
        }
    }

    const int cblk = tid & 31;  const int c0 = cblk * 4;
    const int rblk = tid >> 5;
    float acc[4][4] = {};

    for (int kt = 0; kt < 2; ++kt) {
        __syncthreads();
        {
            const float4* Wg = (const float4*)(W1 + kt * 64 * HIDD);
            float4* Ws = (float4*)Wl;
#pragma unroll
            for (int i = 0; i < 8; ++i) Ws[tid + i * 256] = Wg[tid + i * 256];
        }
        __syncthreads();
#pragma unroll 4
        for (int k = 0; k < 64; k += 4) {
            float4 rv[4];
#pragma unroll
            for (int r = 0; r < 4; ++r)
                rv[r] = *(const float4*)&Rl[(rblk * 4 + r) * INF + kt * 64 + k];
            float4 wv[4];
#pragma unroll
            for (int kk = 0; kk < 4; ++kk)
                wv[kk] = *(const float4*)&Wl[(k + kk) * HIDD + c0];
#pragma unroll
            for (int r = 0; r < 4; ++r) {
                float rr[4] = {rv[r].x, rv[r].y, rv[r].z, rv[r].w};
#pragma unroll
                for (int kk = 0; kk < 4; ++kk) {
                    acc[r][0] += rr[kk] * wv[kk].x;
                    acc[r][1] += rr[kk] * wv[kk].y;
                    acc[r][2] += rr[kk] * wv[kk].z;
                    acc[r][3] += rr[kk] * wv[kk].w;
                }
            }
        }
    }

    const float4 bb = *(const float4*)&b1[c0];
#pragma unroll
    for (int r = 0; r < 4; ++r) {
        int row = r0 + rblk * 4 + r;
        float4 o;
        o.x = fmaxf(acc[r][0] + bb.x, 0.0f);
        o.y = fmaxf(acc[r][1] + bb.y, 0.0f);
        o.z = fmaxf(acc[r][2] + bb.z, 0.0f);
        o.w = fmaxf(acc[r][3] + bb.w, 0.0f);
        *(float4*)&agg[(size_t)row * HIDD + c0] = o;
    }
}

// GEMM2 (weight-first): hw_bf16 = bf16((h @ W2) * src_norm).
__global__ __launch_bounds__(320) void gemm2_kernel(const float* __restrict__ h,
                                                    const float* __restrict__ W2,
                                                    const float* __restrict__ src_norm,
                                                    unsigned short* __restrict__ hwb) {
    __shared__ float Wl[HIDD * NC];
    __shared__ float Rl[64 * HIDD];
    const int tid = threadIdx.x;
    const int r0 = blockIdx.x * 64;

    for (int i = tid; i < HIDD * NC; i += 320) Wl[i] = W2[i];
    {
        const float4* Hg = (const float4*)(h + (size_t)r0 * HIDD);
        float4* Rs = (float4*)Rl;
        for (int j = tid; j < 64 * HIDD / 4; j += 320) {
            int row = j >> 5;
            float4 v = make_float4(0.f, 0.f, 0.f, 0.f);
            if (r0 + row < NN) v = Hg[j];
            Rs[j] = v;
        }
    }
    __syncthreads();

    const int c  = tid % 40;
    const int rg = tid / 40;
    float acc[8] = {};
#pragma unroll 4
    for (int k = 0; k < HIDD; k += 4) {
        float w0 = Wl[(k + 0) * NC + c];
        float w1 = Wl[(k + 1) * NC + c];
        float w2 = Wl[(k + 2) * NC + c];
        float w3 = Wl[(k + 3) * NC + c];
#pragma unroll
        for (int r = 0; r < 8; ++r) {
            float4 rv = *(const float4*)&Rl[(rg * 8 + r) * HIDD + k];
            acc[r] += rv.x * w0 + rv.y * w1 + rv.z * w2 + rv.w * w3;
        }
    }
#pragma unroll
    for (int r = 0; r < 8; ++r) {
        int row = r0 + rg * 8 + r;
        if (row < NN) hwb[(size_t)row * NC + c] = f2bf(acc[r] * src_norm[row]);
    }
}

// one wave per node, lanes 0..39: out[node] = (sum hw_bf16[esrc[e]]) * dst_norm + b2
__global__ __launch_bounds__(256) void gather2_kernel(const int* __restrict__ row_ptr,
                                                      const int* __restrict__ esrc,
                                                      const unsigned short* __restrict__ hwb,
                                                      const float* __restrict__ dst_norm,
                                                      const float* __restrict__ b2,
                                                      float* __restrict__ out) {
    int node = (blockIdx.x * blockDim.x + threadIdx.x) >> 6;
    int lane = threadIdx.x & 63;
    if (node >= NN || lane >= NC) return;
    int beg = __builtin_amdgcn_readfirstlane(row_ptr[node]);
    int end = __builtin_amdgcn_readfirstlane(row_ptr[node + 1]);
    float acc = 0.f;
    int e = beg;
    for (; e + 4 <= end; e += 4) {
        int s0 = esrc[e + 0];
        int s1 = esrc[e + 1];
        int s2 = esrc[e + 2];
        int s3 = esrc[e + 3];
        unsigned int a0 = hwb[(size_t)s0 * NC + lane];
        unsigned int a1 = hwb[(size_t)s1 * NC + lane];
        unsigned int a2 = hwb[(size_t)s2 * NC + lane];
        unsigned int a3 = hwb[(size_t)s3 * NC + lane];
        acc += bflo(a0) + bflo(a1) + bflo(a2) + bflo(a3);
    }
    for (; e < end; ++e) {
        acc += bflo((unsigned int)hwb[(size_t)esrc[e] * NC + lane]);
    }
    out[(size_t)node * NC + lane] = acc * dst_norm[node] + b2[lane];
}

extern "C" void kernel_launch(void* const* d_in, const int* in_sizes, int n_in,
                              void* d_out, int out_size, void* d_ws, size_t ws_size,
                              hipStream_t stream) {
    const float* x   = (const float*)d_in[0];
    const float* W1  = (const float*)d_in[1];
    const float* b1  = (const float*)d_in[2];
    const float* W2  = (const float*)d_in[3];
    const float* b2  = (const float*)d_in[4];
    const int*   src = (const int*)d_in[5];
    const int*   dst = (const int*)d_in[6];
    float* out = (float*)d_out;

    // workspace (4B units):
    // deg_out[NN] | bucket_cnt[256] | bucket_base[256] | bucket_cursor[256] |
    // row_ptr[NN+1] | dstn[NN] | esrc[NE] | pad | agg[NN*128 f32] | xh[NN*128 bf16]
    // hwb (bf16, NN*40) ALIASES xh (xh dead after gather1, before gemm2 writes hwb).
    unsigned int* deg_out      = (unsigned int*)d_ws;
    unsigned int* bucket_cnt   = deg_out + NN;
    int* bucket_base   = (int*)(bucket_cnt + 256);
    int* bucket_cursor = bucket_base + 256;
    int* row_ptr = bucket_cursor + 256;
    float* dstn  = (float*)(row_ptr + NN + 1);
    int* esrc    = (int*)(dstn + NN);
    size_t ofs = (size_t)NN + 768 + (NN + 1) + NN + NE;
    ofs = (ofs + 3) & ~(size_t)3;                 // 16B align
    float* agg = (float*)d_ws + ofs;
    unsigned short* xh  = (unsigned short*)(agg + (size_t)NN * INF);
    unsigned short* hwb = xh;                     // alias — see lifetime note above

    // eparts scratch lives in d_out (6.4 MB of 16 MB) — dead before gather2 writes
    int* eparts = (int*)d_out;

    hipMemsetAsync(deg_out, 0, ((size_t)NN + 256) * sizeof(int), stream);

    convert_kernel<<<(NN * INF / 8 + 255) / 256, 256, 0, stream>>>(x, xh);
    hist_kernel<<<391, 256, 0, stream>>>(src, dst, deg_out, bucket_cnt);
    bucket_scan_kernel<<<1, 256, 0, stream>>>(bucket_cnt, bucket_base, bucket_cursor);
    partition_kernel<<<PBLK, 256, 0, stream>>>(src, dst, bucket_cursor, eparts);
    pass2_kernel<<<NBK, 512, 0, stream>>>(eparts, bucket_base, row_ptr, esrc, deg_out, dstn);
    // src_norm = (float*)deg_out, dst_norm = dstn (written by pass2)
    gather1_kernel<<<(NN * 64 + 255) / 256, 256, 0, stream>>>(row_ptr, esrc, xh,
                                                              (const float*)deg_out, agg);
    gemm1_kernel<<<NN / 32, 256, 0, stream>>>(agg, W1, b1, dstn);
    gemm2_kernel<<<(NN + 63) / 64, 320, 0, stream>>>(agg, W2, (const float*)deg_out, hwb);
    gather2_kernel<<<(NN * 64 + 255) / 256, 256, 0, stream>>>(row_ptr, esrc, hwb,
                                                              dstn, b2, out);
}

// Round 7
// 393.146 us; speedup vs baseline: 5.0356x; 1.2289x over previous
//
#include <hip/hip_runtime.h>

// GCN: 2-layer GraphConv, N=100000, E=1600000, 128 -> 128 -> 40 (fp32).
// Round 7: MFMA-fused gemm12 (bf16, one kernel replaces gemm1+gemm2, h stays in LDS),
// bf16 agg, bucket_scan folded into partition/pass2, W-transposes folded into convert.
//   memset -> convert(x->xh, W1->W1t, W2->W2t bf16) -> hist -> partition -> pass2 ->
//   gather1(bf16 out) -> gemm12(MFMA, dstn/b1/relu + W2 + srcn fused) -> gather2
constexpr int NN   = 100000;
constexpr int NE   = 1600000;
constexpr int INF  = 128;
constexpr int NC   = 40;

constexpr int BKSH = 9;                        // 512 nodes per coarse bucket
constexpr int NBK  = (NN + 511) / 512;         // 196 buckets
constexpr int EPB  = 8192;                     // edges per partition block
constexpr int PBLK = (NE + EPB - 1) / EPB;     // 196
constexpr int CAP  = 14336;                    // pass2 LDS esrc capacity (56 KB)

typedef __attribute__((ext_vector_type(8))) short short8;
typedef __attribute__((ext_vector_type(4))) float f32x4;

__device__ __forceinline__ float bflo(unsigned int u) { return __uint_as_float(u << 16); }
__device__ __forceinline__ float bfhi(unsigned int u) { return __uint_as_float(u & 0xffff0000u); }
__device__ __forceinline__ unsigned short f2bf(float f) {          // RNE
    unsigned int u = __float_as_uint(f);
    return (unsigned short)((u + 0x7fffu + ((u >> 16) & 1u)) >> 16);
}
__device__ __forceinline__ unsigned int pack2(float a, float b) {
    return (unsigned int)f2bf(a) | ((unsigned int)f2bf(b) << 16);
}

// blocks 0..6249: x (fp32) -> xh (bf16), 8 floats/thread.
// block 6250: W1 (128x128, k-major) -> W1t bf16 (n-major).
// block 6251: W2 (128x40) -> W2t bf16 [48][128] (n-major, cols 40..47 zero).
__global__ __launch_bounds__(256) void convert_kernel(const float* __restrict__ x,
                                                      const float* __restrict__ W1,
                                                      const float* __restrict__ W2,
                                                      unsigned short* __restrict__ xh,
                                                      unsigned short* __restrict__ w1t,
                                                      unsigned short* __restrict__ w2t) {
    const int b = blockIdx.x;
    if (b < 6250) {
        int j = b * 256 + threadIdx.x;               // uint4 index, N*128/8 = 1.6M
        float4 v0 = ((const float4*)x)[2 * j];
        float4 v1 = ((const float4*)x)[2 * j + 1];
        uint4 o;
        o.x = pack2(v0.x, v0.y);
        o.y = pack2(v0.z, v0.w);
        o.z = pack2(v1.x, v1.y);
        o.w = pack2(v1.z, v1.w);
        ((uint4*)xh)[j] = o;
    } else if (b == 6250) {
        for (int i = threadIdx.x; i < 128 * 128; i += 256) {
            int k = i >> 7, n = i & 127;
            w1t[n * 128 + k] = f2bf(W1[i]);
        }
    } else {
        for (int i = threadIdx.x; i < 48 * 128; i += 256) {
            int n = i >> 7, k = i & 127;
            w2t[i] = f2bf((n < NC) ? W2[k * NC + n] : 0.f);
        }
    }
}

// coarse dst histogram (LDS-aggregated) + src out-degree histogram
__global__ __launch_bounds__(256) void hist_kernel(const int* __restrict__ src,
                                                   const int* __restrict__ dst,
                                                   unsigned int* __restrict__ deg_out,
                                                   unsigned int* __restrict__ bucket_cnt) {
    __shared__ unsigned int hc[NBK];
    const int tid = threadIdx.x;
    for (int i = tid; i < NBK; i += 256) hc[i] = 0u;
    __syncthreads();
    int gid = blockIdx.x * 256 + tid;
    int stride = gridDim.x * 256;
    for (int e = gid; e < NE; e += stride) {
        atomicAdd(&deg_out[src[e]], 1u);
        atomicAdd(&hc[dst[e] >> BKSH], 1u);
    }
    __syncthreads();
    for (int i = tid; i < NBK; i += 256)
        if (hc[i]) atomicAdd(&bucket_cnt[i], hc[i]);
}

// partition edges into coarse buckets, LDS-staged so global writes are coalesced runs.
// Self-scans bucket_cnt -> base (no separate scan kernel); cursor is zero-based.
// record = src | (dst_local << 17)   (src < 2^17, dst_local < 512)
__global__ __launch_bounds__(256) void partition_kernel(const int* __restrict__ src,
                                                        const int* __restrict__ dst,
                                                        const unsigned int* __restrict__ bucket_cnt,
                                                        int* __restrict__ cursor,
                                                        int* __restrict__ eparts) {
    __shared__ int sc[256];
    __shared__ int basel[NBK];
    __shared__ int cnt[NBK];
    __shared__ int gadj[NBK];
    __shared__ int cur[NBK];
    __shared__ int stage[EPB];
    __shared__ unsigned char bid[EPB];
    const int tid = threadIdx.x;
    const int e0 = blockIdx.x * EPB;
    const int total = min(EPB, NE - e0);

    // self-scan of bucket_cnt -> basel
    {
        int v = (tid < NBK) ? (int)bucket_cnt[tid] : 0;
        sc[tid] = v;
        __syncthreads();
        for (int off = 1; off < 256; off <<= 1) {
            int t = (tid >= off) ? sc[tid - off] : 0;
            __syncthreads();
            sc[tid] += t;
            __syncthreads();
        }
        if (tid < NBK) basel[tid] = sc[tid] - v;
    }
    for (int i = tid; i < NBK; i += 256) cnt[i] = 0;
    __syncthreads();
    // phase A: count per bucket
    for (int i = tid; i < total; i += 256)
        atomicAdd(&cnt[dst[e0 + i] >> BKSH], 1);
    __syncthreads();
    // exclusive scan of cnt
    int v = (tid < NBK) ? cnt[tid] : 0;
    sc[tid] = v;
    __syncthreads();
    for (int off = 1; off < 256; off <<= 1) {
        int t = (tid >= off) ? sc[tid - off] : 0;
        __syncthreads();
        sc[tid] += t;
        __syncthreads();
    }
    if (tid < NBK) {
        int excl = sc[tid] - v;
        cur[tid] = excl;
        int g = (v > 0) ? atomicAdd(&cursor[tid], v) : 0;   // zero-based
        gadj[tid] = basel[tid] + g - excl;
    }
    __syncthreads();
    // phase B: re-read edges, stage grouped by bucket
    for (int i = tid; i < total; i += 256) {
        int s = src[e0 + i];
        int d = dst[e0 + i];
        int b = d >> BKSH;
        int dl = d - (b << BKSH);
        int off = atomicAdd(&cur[b], 1);
        stage[off] = s | (dl << 17);
        bid[off] = (unsigned char)b;
    }
    __syncthreads();
    // dump: consecutive j within a bucket-run -> consecutive global addresses
    for (int j = tid; j < total; j += 256) {
        int b = bid[j];
        eparts[gadj[b] + j] = stage[j];
    }
}

// per-bucket fine CSR: self-scan for base, local hist + scan + LDS scatter ->
// row_ptr, dst_norm, src_norm (in-place convert), esrc (coalesced dump).
__global__ __launch_bounds__(512) void pass2_kernel(const int* __restrict__ eparts,
                                                    const unsigned int* __restrict__ bucket_cnt,
                                                    int* __restrict__ row_ptr,
                                                    int* __restrict__ esrc,
                                                    unsigned int* __restrict__ deg_out,
                                                    float* __restrict__ dstn) {
    __shared__ int hist[512];
    __shared__ int cur[512];
    __shared__ int lesrc[CAP];
    __shared__ int base_s, cnt_s;
    const int tid = threadIdx.x;
    const int b = blockIdx.x;

    // self-scan of bucket_cnt -> base for this bucket
    {
        int v = (tid < NBK) ? (int)bucket_cnt[tid] : 0;
        hist[tid] = v;
        __syncthreads();
        for (int off = 1; off < 512; off <<= 1) {
            int t = (tid >= off) ? hist[tid - off] : 0;
            __syncthreads();
            hist[tid] += t;
            __syncthreads();
        }
        if (tid == b) { base_s = hist[b] - v; cnt_s = v; }   // b < NBK <= 512
        __syncthreads();
    }
    const int base = base_s;
    const int cnt = cnt_s;
    const int n0 = b << BKSH;
    const int nloc = min(512, NN - n0);

    hist[tid] = 0;
    __syncthreads();
    for (int j = tid; j < cnt; j += 512)
        atomicAdd(&hist[eparts[base + j] >> 17], 1);
    __syncthreads();
    int myc = hist[tid];
    for (int off = 1; off < 512; off <<= 1) {
        int t = (tid >= off) ? hist[tid - off] : 0;
        __syncthreads();
        hist[tid] += t;
        __syncthreads();
    }
    int excl = hist[tid] - myc;
    cur[tid] = excl;
    if (tid < nloc) {
        int g = n0 + tid;
        row_ptr[g] = base + excl;
        dstn[g] = rsqrtf(fmaxf((float)myc, 1.0f));                    // dst_norm
        float sd = (float)deg_out[g];
        ((float*)deg_out)[g] = rsqrtf(fmaxf(sd, 1.0f));               // src_norm in place
    }
    if (b == NBK - 1 && tid == 0) row_ptr[NN] = NE;
    __syncthreads();
    if (cnt <= CAP) {
        for (int j = tid; j < cnt; j += 512) {
            int rec = eparts[base + j];
            int pos = atomicAdd(&cur[rec >> 17], 1);
            lesrc[pos] = rec & 0x1FFFF;
        }
        __syncthreads();
        for (int j = tid; j < cnt; j += 512) esrc[base + j] = lesrc[j];
    } else {
        for (int j = tid; j < cnt; j += 512) {
            int rec = eparts[base + j];
            int pos = atomicAdd(&cur[rec >> 17], 1);
            esrc[base + pos] = rec & 0x1FFFF;
        }
    }
}

// one wave per node: aggb[node] = bf16( sum x_bf16[esrc[e]] * src_norm[esrc[e]] )
// half-waves over edge pairs; uint2 (4 bf16)/lane; 16 edges in flight; fp32 acc.
__global__ __launch_bounds__(256) void gather1_kernel(const int* __restrict__ row_ptr,
                                                      const int* __restrict__ esrc,
                                                      const unsigned short* __restrict__ xh,
                                                      const float* __restrict__ src_norm,
                                                      unsigned short* __restrict__ aggb) {
    int node = (blockIdx.x * blockDim.x + threadIdx.x) >> 6;
    int lane = threadIdx.x & 63;
    if (node >= NN) return;
    int beg = __builtin_amdgcn_readfirstlane(row_ptr[node]);
    int end = __builtin_amdgcn_readfirstlane(row_ptr[node + 1]);
    const int half = lane >> 5;
    const int l32  = lane & 31;
    float4 acc = make_float4(0.f, 0.f, 0.f, 0.f);
    int e = beg;
    for (; e + 16 <= end; e += 16) {
        int s0 = esrc[e + 0 + half];
        int s1 = esrc[e + 2 + half];
        int s2 = esrc[e + 4 + half];
        int s3 = esrc[e + 6 + half];
        int s4 = esrc[e + 8 + half];
        int s5 = esrc[e + 10 + half];
        int s6 = esrc[e + 12 + half];
        int s7 = esrc[e + 14 + half];
        float n0 = src_norm[s0], n1 = src_norm[s1], n2 = src_norm[s2], n3 = src_norm[s3];
        float n4 = src_norm[s4], n5 = src_norm[s5], n6 = src_norm[s6], n7 = src_norm[s7];
        uint2 u0 = ((const uint2*)(xh + (size_t)s0 * INF))[l32];
        uint2 u1 = ((const uint2*)(xh + (size_t)s1 * INF))[l32];
        uint2 u2 = ((const uint2*)(xh + (size_t)s2 * INF))[l32];
        uint2 u3 = ((const uint2*)(xh + (size_t)s3 * INF))[l32];
        uint2 u4 = ((const uint2*)(xh + (size_t)s4 * INF))[l32];
        uint2 u5 = ((const uint2*)(xh + (size_t)s5 * INF))[l32];
        uint2 u6 = ((const uint2*)(xh + (size_t)s6 * INF))[l32];
        uint2 u7 = ((const uint2*)(xh + (size_t)s7 * INF))[l32];
        acc.x += bflo(u0.x) * n0; acc.y += bfhi(u0.x) * n0; acc.z += bflo(u0.y) * n0; acc.w += bfhi(u0.y) * n0;
        acc.x += bflo(u1.x) * n1; acc.y += bfhi(u1.x) * n1; acc.z += bflo(u1.y) * n1; acc.w += bfhi(u1.y) * n1;
        acc.x += bflo(u2.x) * n2; acc.y += bfhi(u2.x) * n2; acc.z += bflo(u2.y) * n2; acc.w += bfhi(u2.y) * n2;
        acc.x += bflo(u3.x) * n3; acc.y += bfhi(u3.x) * n3; acc.z += bflo(u3.y) * n3; acc.w += bfhi(u3.y) * n3;
        acc.x += bflo(u4.x) * n4; acc.y += bfhi(u4.x) * n4; acc.z += bflo(u4.y) * n4; acc.w += bfhi(u4.y) * n4;
        acc.x += bflo(u5.x) * n5; acc.y += bfhi(u5.x) * n5; acc.z += bflo(u5.y) * n5; acc.w += bfhi(u5.y) * n5;
        acc.x += bflo(u6.x) * n6; acc.y += bfhi(u6.x) * n6; acc.z += bflo(u6.y) * n6; acc.w += bfhi(u6.y) * n6;
        acc.x += bflo(u7.x) * n7; acc.y += bfhi(u7.x) * n7; acc.z += bflo(u7.y) * n7; acc.w += bfhi(u7.y) * n7;
    }
    for (; e + 2 <= end; e += 2) {
        int s0 = esrc[e + half];
        float n0 = src_norm[s0];
        uint2 u0 = ((const uint2*)(xh + (size_t)s0 * INF))[l32];
        acc.x += bflo(u0.x) * n0; acc.y += bfhi(u0.x) * n0; acc.z += bflo(u0.y) * n0; acc.w += bfhi(u0.y) * n0;
    }
    if (e < end && half == 0) {
        int s0 = esrc[e];
        float n0 = src_norm[s0];
        uint2 u0 = ((const uint2*)(xh + (size_t)s0 * INF))[l32];
        acc.x += bflo(u0.x) * n0; acc.y += bfhi(u0.x) * n0; acc.z += bflo(u0.y) * n0; acc.w += bfhi(u0.y) * n0;
    }
    acc.x += __shfl_down(acc.x, 32);
    acc.y += __shfl_down(acc.y, 32);
    acc.z += __shfl_down(acc.z, 32);
    acc.w += __shfl_down(acc.w, 32);
    if (half == 0) {
        uint2 o;
        o.x = pack2(acc.x, acc.y);
        o.y = pack2(acc.z, acc.w);
        ((uint2*)(aggb + (size_t)node * INF))[l32] = o;
    }
}

// Fused GEMM1+GEMM2 via MFMA 16x16x32 bf16. 64 rows/block, 256 threads = 4 waves,
// each wave owns 16 rows (A-frags wave-private; only 2 barriers needed).
// h = relu(dstn*(agg@W1) + b1) computed into LDS (bf16), then out = (h@W2)*srcn -> hwb.
// Verified layouts (m89/m92): A[m=lane&15][k=(lane>>4)*8+j]; B-frag from B^T rows;
// C/D: col=lane&15, row=(lane>>4)*4+reg.
__global__ __launch_bounds__(256) void gemm12_kernel(const unsigned short* __restrict__ aggb,
                                                     const unsigned short* __restrict__ w1t,
                                                     const unsigned short* __restrict__ w2t,
                                                     const float* __restrict__ b1,
                                                     const float* __restrict__ dstn,
                                                     const float* __restrict__ srcn,
                                                     unsigned short* __restrict__ hwb) {
    __shared__ unsigned short At[64 * 128];    // 16 KB: agg tile, then h tile
    __shared__ unsigned short W1l[128 * 128];  // 32 KB
    __shared__ unsigned short W2l[48 * 128];   // 12 KB
    __shared__ float dn[64], sn[64], b1l[128];
    const int tid = threadIdx.x;
    const int r0 = blockIdx.x * 64;

    {   // stage weights (uint4 = 8 bf16)
        const uint4* g1 = (const uint4*)w1t;
        uint4* s1 = (uint4*)W1l;
        for (int i = tid; i < 2048; i += 256) s1[i] = g1[i];
        const uint4* g2 = (const uint4*)w2t;
        uint4* s2 = (uint4*)W2l;
        for (int i = tid; i < 768; i += 256) s2[i] = g2[i];
    }
    {   // stage agg tile (zero-pad rows >= NN): 64 rows x 128 bf16 = 1024 uint4
        const uint4* g = (const uint4*)(aggb + (size_t)r0 * 128);
        uint4* s = (uint4*)At;
        for (int i = tid; i < 1024; i += 256) {
            int row = i >> 4;
            uint4 v = make_uint4(0, 0, 0, 0);
            if (r0 + row < NN) v = g[i];
            s[i] = v;
        }
    }
    if (tid < 64) {
        int r = r0 + tid;
        dn[tid] = (r < NN) ? dstn[r] : 0.f;
        sn[tid] = (r < NN) ? srcn[r] : 0.f;
    }
    if (tid >= 64 && tid < 192) b1l[tid - 64] = b1[tid - 64];
    __syncthreads();

    const int wv    = tid >> 6;      // wave id -> rows wv*16..+15
    const int lane  = tid & 63;
    const int lrow  = lane & 15;     // A-row within tile / D col
    const int lquad = lane >> 4;     // k-chunk / D row base = lquad*4

    // stage 1: h = relu(dn * (agg @ W1) + b1), written back into At as bf16
    short8 afrag[4];
#pragma unroll
    for (int ks = 0; ks < 4; ++ks)
        afrag[ks] = *(const short8*)&At[(wv * 16 + lrow) * 128 + ks * 32 + lquad * 8];
    float hreg[8][4];
#pragma unroll
    for (int nt = 0; nt < 8; ++nt) {
        f32x4 acc = {0.f, 0.f, 0.f, 0.f};
#pragma unroll
        for (int ks = 0; ks < 4; ++ks) {
            short8 bfr = *(const short8*)&W1l[(nt * 16 + lrow) * 128 + ks * 32 + lquad * 8];
            acc = __builtin_amdgcn_mfma_f32_16x16x32_bf16(afrag[ks], bfr, acc, 0, 0, 0);
        }
#pragma unroll
        for (int i = 0; i < 4; ++i) hreg[nt][i] = acc[i];
    }
    // write h into At (each wave touches only its own 16 rows)
#pragma unroll
    for (int nt = 0; nt < 8; ++nt) {
        int col = nt * 16 + lrow;
        float bb = b1l[col];
#pragma unroll
        for (int i = 0; i < 4; ++i) {
            int row = wv * 16 + lquad * 4 + i;
            At[row * 128 + col] = f2bf(fmaxf(hreg[nt][i] * dn[row] + bb, 0.f));
        }
    }
    __syncthreads();   // ensure h visible to this wave's ds_reads (ordering)

    // stage 2: out = (h @ W2) * srcn -> hwb (cols 0..39; 40..47 are zero pad)
#pragma unroll
    for (int ks = 0; ks < 4; ++ks)
        afrag[ks] = *(const short8*)&At[(wv * 16 + lrow) * 128 + ks * 32 + lquad * 8];
#pragma unroll
    for (int nt = 0; nt < 3; ++nt) {
        f32x4 acc = {0.f, 0.f, 0.f, 0.f};
#pragma unroll
        for (int ks = 0; ks < 4; ++ks) {
            short8 bfr = *(const short8*)&W2l[(nt * 16 + lrow) * 128 + ks * 32 + lquad * 8];
            acc = __builtin_amdgcn_mfma_f32_16x16x32_bf16(afrag[ks], bfr, acc, 0, 0, 0);
        }
        int col = nt * 16 + lrow;
        if (col < NC) {
#pragma unroll
            for (int i = 0; i < 4; ++i) {
                int row = wv * 16 + lquad * 4 + i;
                int grow = r0 + row;
                if (grow < NN)
                    hwb[(size_t)grow * NC + col] = f2bf(acc[i] * sn[row]);
            }
        }
    }
}

// one wave per node, lanes 0..39: out[node] = (sum hw_bf16[esrc[e]]) * dst_norm + b2
// 8 edges in flight.
__global__ __launch_bounds__(256) void gather2_kernel(const int* __restrict__ row_ptr,
                                                      const int* __restrict__ esrc,
                                                      const unsigned short* __restrict__ hwb,
                                                      const float* __restrict__ dst_norm,
                                                      const float* __restrict__ b2,
                                                      float* __restrict__ out) {
    int node = (blockIdx.x * blockDim.x + threadIdx.x) >> 6;
    int lane = threadIdx.x & 63;
    if (node >= NN || lane >= NC) return;
    int beg = __builtin_amdgcn_readfirstlane(row_ptr[node]);
    int end = __builtin_amdgcn_readfirstlane(row_ptr[node + 1]);
    float acc = 0.f;
    int e = beg;
    for (; e + 8 <= end; e += 8) {
        int s0 = esrc[e + 0];
        int s1 = esrc[e + 1];
        int s2 = esrc[e + 2];
        int s3 = esrc[e + 3];
        int s4 = esrc[e + 4];
        int s5 = esrc[e + 5];
        int s6 = esrc[e + 6];
        int s7 = esrc[e + 7];
        unsigned int a0 = hwb[(size_t)s0 * NC + lane];
        unsigned int a1 = hwb[(size_t)s1 * NC + lane];
        unsigned int a2 = hwb[(size_t)s2 * NC + lane];
        unsigned int a3 = hwb[(size_t)s3 * NC + lane];
        unsigned int a4 = hwb[(size_t)s4 * NC + lane];
        unsigned int a5 = hwb[(size_t)s5 * NC + lane];
        unsigned int a6 = hwb[(size_t)s6 * NC + lane];
        unsigned int a7 = hwb[(size_t)s7 * NC + lane];
        acc += bflo(a0) + bflo(a1) + bflo(a2) + bflo(a3)
             + bflo(a4) + bflo(a5) + bflo(a6) + bflo(a7);
    }
    for (; e < end; ++e) {
        acc += bflo((unsigned int)hwb[(size_t)esrc[e] * NC + lane]);
    }
    out[(size_t)node * NC + lane] = acc * dst_norm[node] + b2[lane];
}

extern "C" void kernel_launch(void* const* d_in, const int* in_sizes, int n_in,
                              void* d_out, int out_size, void* d_ws, size_t ws_size,
                              hipStream_t stream) {
    const float* x   = (const float*)d_in[0];
    const float* W1  = (const float*)d_in[1];
    const float* b1  = (const float*)d_in[2];
    const float* W2  = (const float*)d_in[3];
    const float* b2  = (const float*)d_in[4];
    const int*   src = (const int*)d_in[5];
    const int*   dst = (const int*)d_in[6];
    float* out = (float*)d_out;

    // workspace (4B units):
    // deg_out[NN] | bucket_cnt[256] | cursor[256] | row_ptr[NN+1] | dstn[NN] |
    // esrc[NE] | pad | aggb[NN*64] | xh[NN*64] | w1t[8192] | w2t[3072]
    // hwb (bf16 NN*40) ALIASES xh (xh dead after gather1, hwb written by gemm12 after).
    unsigned int* deg_out    = (unsigned int*)d_ws;
    unsigned int* bucket_cnt = deg_out + NN;
    int* cursor  = (int*)(bucket_cnt + 256);
    int* row_ptr = cursor + 256;
    float* dstn  = (float*)(row_ptr + NN + 1);
    int* esrc    = (int*)(dstn + NN);
    size_t ofs = (size_t)NN + 512 + (NN + 1) + NN + NE;
    ofs = (ofs + 3) & ~(size_t)3;                 // 16B align
    unsigned short* aggb = (unsigned short*)((float*)d_ws + ofs);
    unsigned short* xh   = aggb + (size_t)NN * INF;
    unsigned short* w1t  = xh + (size_t)NN * INF;
    unsigned short* w2t  = w1t + 128 * 128;
    unsigned short* hwb  = xh;                    // alias — see lifetime note above

    // eparts scratch lives in d_out (6.4 MB of 16 MB) — dead before gather2 writes
    int* eparts = (int*)d_out;

    hipMemsetAsync(deg_out, 0, ((size_t)NN + 512) * sizeof(int), stream);

    convert_kernel<<<6252, 256, 0, stream>>>(x, W1, W2, xh, w1t, w2t);
    hist_kernel<<<391, 256, 0, stream>>>(src, dst, deg_out, bucket_cnt);
    partition_kernel<<<PBLK, 256, 0, stream>>>(src, dst, bucket_cnt, cursor, eparts);
    pass2_kernel<<<NBK, 512, 0, stream>>>(eparts, bucket_cnt, row_ptr, esrc, deg_out, dstn);
    // src_norm = (float*)deg_out, dst_norm = dstn (written by pass2)
    gather1_kernel<<<(NN * 64 + 255) / 256, 256, 0, stream>>>(row_ptr, esrc, xh,
                                                              (const float*)deg_out, aggb);
    gemm12_kernel<<<(NN + 63) / 64, 256, 0, stream>>>(aggb, w1t, w2t, b1, dstn,
                                                      (const float*)deg_out, hwb);
    gather2_kernel<<<(NN * 64 + 255) / 256, 256, 0, stream>>>(row_ptr, esrc, hwb,
                                                              dstn, b2, out);
}

// Round 8
// 378.949 us; speedup vs baseline: 5.2243x; 1.0375x over previous
//
#include <hip/hip_runtime.h>

// GCN: 2-layer GraphConv, N=100000, E=1600000, 128 -> 128 -> 40 (fp32).
// Round 8: convert merged into hist (co-scheduled), partition EPB 4096 (2x blocks),
// gather2 restructured to 6 edges/wave-step (10 lanes x uint2 each + shfl reduce).
//   memset -> histconv -> partition -> pass2 -> gather1(bf16) ->
//   gemm12(MFMA, fused) -> gather2(fused epilogue)
constexpr int NN   = 100000;
constexpr int NE   = 1600000;
constexpr int INF  = 128;
constexpr int NC   = 40;

constexpr int BKSH = 9;                        // 512 nodes per coarse bucket
constexpr int NBK  = (NN + 511) / 512;         // 196 buckets
constexpr int EPB  = 4096;                     // edges per partition block
constexpr int PBLK = (NE + EPB - 1) / EPB;     // 391
constexpr int CAP  = 14336;                    // pass2 LDS esrc capacity (56 KB)
constexpr int HB   = 391;                      // hist blocks in merged kernel

typedef __attribute__((ext_vector_type(8))) short short8;
typedef __attribute__((ext_vector_type(4))) float f32x4;

__device__ __forceinline__ float bflo(unsigned int u) { return __uint_as_float(u << 16); }
__device__ __forceinline__ float bfhi(unsigned int u) { return __uint_as_float(u & 0xffff0000u); }
__device__ __forceinline__ unsigned short f2bf(float f) {          // RNE
    unsigned int u = __float_as_uint(f);
    return (unsigned short)((u + 0x7fffu + ((u >> 16) & 1u)) >> 16);
}
__device__ __forceinline__ unsigned int pack2(float a, float b) {
    return (unsigned int)f2bf(a) | ((unsigned int)f2bf(b) << 16);
}

// blocks 0..HB-1: coarse dst histogram (LDS) + src out-degree histogram (global).
// blocks HB..HB+6249: x (fp32) -> xh (bf16), 8 floats/thread.
// block HB+6250: W1 -> W1t bf16 (n-major). block HB+6251: W2 -> W2t bf16 [48][128].
__global__ __launch_bounds__(256) void histconv_kernel(const int* __restrict__ src,
                                                       const int* __restrict__ dst,
                                                       unsigned int* __restrict__ deg_out,
                                                       unsigned int* __restrict__ bucket_cnt,
                                                       const float* __restrict__ x,
                                                       const float* __restrict__ W1,
                                                       const float* __restrict__ W2,
                                                       unsigned short* __restrict__ xh,
                                                       unsigned short* __restrict__ w1t,
                                                       unsigned short* __restrict__ w2t) {
    const int b = blockIdx.x;
    const int tid = threadIdx.x;
    if (b < HB) {
        __shared__ unsigned int hc[NBK];
        for (int i = tid; i < NBK; i += 256) hc[i] = 0u;
        __syncthreads();
        int gid = b * 256 + tid;
        int stride = HB * 256;
        for (int e = gid; e < NE; e += stride) {
            atomicAdd(&deg_out[src[e]], 1u);
            atomicAdd(&hc[dst[e] >> BKSH], 1u);
        }
        __syncthreads();
        for (int i = tid; i < NBK; i += 256)
            if (hc[i]) atomicAdd(&bucket_cnt[i], hc[i]);
    } else if (b < HB + 6250) {
        int j = (b - HB) * 256 + tid;                // uint4 index, N*128/8 = 1.6M
        float4 v0 = ((const float4*)x)[2 * j];
        float4 v1 = ((const float4*)x)[2 * j + 1];
        uint4 o;
        o.x = pack2(v0.x, v0.y);
        o.y = pack2(v0.z, v0.w);
        o.z = pack2(v1.x, v1.y);
        o.w = pack2(v1.z, v1.w);
        ((uint4*)xh)[j] = o;
    } else if (b == HB + 6250) {
        for (int i = tid; i < 128 * 128; i += 256) {
            int k = i >> 7, n = i & 127;
            w1t[n * 128 + k] = f2bf(W1[i]);
        }
    } else {
        for (int i = tid; i < 48 * 128; i += 256) {
            int n = i >> 7, k = i & 127;
            w2t[i] = f2bf((n < NC) ? W2[k * NC + n] : 0.f);
        }
    }
}

// partition edges into coarse buckets, LDS-staged so global writes are coalesced runs.
// Self-scans bucket_cnt -> base; cursor is zero-based.
// record = src | (dst_local << 17)   (src < 2^17, dst_local < 512)
__global__ __launch_bounds__(256) void partition_kernel(const int* __restrict__ src,
                                                        const int* __restrict__ dst,
                                                        const unsigned int* __restrict__ bucket_cnt,
                                                        int* __restrict__ cursor,
                                                        int* __restrict__ eparts) {
    __shared__ int sc[256];
    __shared__ int basel[NBK];
    __shared__ int cnt[NBK];
    __shared__ int gadj[NBK];
    __shared__ int cur[NBK];
    __shared__ int stage[EPB];
    __shared__ unsigned char bid[EPB];
    const int tid = threadIdx.x;
    const int e0 = blockIdx.x * EPB;
    const int total = min(EPB, NE - e0);

    // self-scan of bucket_cnt -> basel
    {
        int v = (tid < NBK) ? (int)bucket_cnt[tid] : 0;
        sc[tid] = v;
        __syncthreads();
        for (int off = 1; off < 256; off <<= 1) {
            int t = (tid >= off) ? sc[tid - off] : 0;
            __syncthreads();
            sc[tid] += t;
            __syncthreads();
        }
        if (tid < NBK) basel[tid] = sc[tid] - v;
    }
    for (int i = tid; i < NBK; i += 256) cnt[i] = 0;
    __syncthreads();
    // phase A: count per bucket
    for (int i = tid; i < total; i += 256)
        atomicAdd(&cnt[dst[e0 + i] >> BKSH], 1);
    __syncthreads();
    // exclusive scan of cnt
    int v = (tid < NBK) ? cnt[tid] : 0;
    sc[tid] = v;
    __syncthreads();
    for (int off = 1; off < 256; off <<= 1) {
        int t = (tid >= off) ? sc[tid - off] : 0;
        __syncthreads();
        sc[tid] += t;
        __syncthreads();
    }
    if (tid < NBK) {
        int excl = sc[tid] - v;
        cur[tid] = excl;
        int g = (v > 0) ? atomicAdd(&cursor[tid], v) : 0;   // zero-based
        gadj[tid] = basel[tid] + g - excl;
    }
    __syncthreads();
    // phase B: re-read edges, stage grouped by bucket
    for (int i = tid; i < total; i += 256) {
        int s = src[e0 + i];
        int d = dst[e0 + i];
        int b = d >> BKSH;
        int dl = d - (b << BKSH);
        int off = atomicAdd(&cur[b], 1);
        stage[off] = s | (dl << 17);
        bid[off] = (unsigned char)b;
    }
    __syncthreads();
    // dump: consecutive j within a bucket-run -> consecutive global addresses
    for (int j = tid; j < total; j += 256) {
        int b = bid[j];
        eparts[gadj[b] + j] = stage[j];
    }
}

// per-bucket fine CSR: self-scan for base, local hist + scan + LDS scatter ->
// row_ptr, dst_norm, src_norm (in-place convert), esrc (coalesced dump).
__global__ __launch_bounds__(512) void pass2_kernel(const int* __restrict__ eparts,
                                                    const unsigned int* __restrict__ bucket_cnt,
                                                    int* __restrict__ row_ptr,
                                                    int* __restrict__ esrc,
                                                    unsigned int* __restrict__ deg_out,
                                                    float* __restrict__ dstn) {
    __shared__ int hist[512];
    __shared__ int cur[512];
    __shared__ int lesrc[CAP];
    __shared__ int base_s, cnt_s;
    const int tid = threadIdx.x;
    const int b = blockIdx.x;

    // self-scan of bucket_cnt -> base for this bucket
    {
        int v = (tid < NBK) ? (int)bucket_cnt[tid] : 0;
        hist[tid] = v;
        __syncthreads();
        for (int off = 1; off < 512; off <<= 1) {
            int t = (tid >= off) ? hist[tid - off] : 0;
            __syncthreads();
            hist[tid] += t;
            __syncthreads();
        }
        if (tid == b) { base_s = hist[b] - v; cnt_s = v; }   // b < NBK <= 512
        __syncthreads();
    }
    const int base = base_s;
    const int cnt = cnt_s;
    const int n0 = b << BKSH;
    const int nloc = min(512, NN - n0);

    hist[tid] = 0;
    __syncthreads();
    for (int j = tid; j < cnt; j += 512)
        atomicAdd(&hist[eparts[base + j] >> 17], 1);
    __syncthreads();
    int myc = hist[tid];
    for (int off = 1; off < 512; off <<= 1) {
        int t = (tid >= off) ? hist[tid - off] : 0;
        __syncthreads();
        hist[tid] += t;
        __syncthreads();
    }
    int excl = hist[tid] - myc;
    cur[tid] = excl;
    if (tid < nloc) {
        int g = n0 + tid;
        row_ptr[g] = base + excl;
        dstn[g] = rsqrtf(fmaxf((float)myc, 1.0f));                    // dst_norm
        float sd = (float)deg_out[g];
        ((float*)deg_out)[g] = rsqrtf(fmaxf(sd, 1.0f));               // src_norm in place
    }
    if (b == NBK - 1 && tid == 0) row_ptr[NN] = NE;
    __syncthreads();
    if (cnt <= CAP) {
        for (int j = tid; j < cnt; j += 512) {
            int rec = eparts[base + j];
            int pos = atomicAdd(&cur[rec >> 17], 1);
            lesrc[pos] = rec & 0x1FFFF;
        }
        __syncthreads();
        for (int j = tid; j < cnt; j += 512) esrc[base + j] = lesrc[j];
    } else {
        for (int j = tid; j < cnt; j += 512) {
            int rec = eparts[base + j];
            int pos = atomicAdd(&cur[rec >> 17], 1);
            esrc[base + pos] = rec & 0x1FFFF;
        }
    }
}

// one wave per node: aggb[node] = bf16( sum x_bf16[esrc[e]] * src_norm[esrc[e]] )
// half-waves over edge pairs; uint2 (4 bf16)/lane; 16 edges in flight; fp32 acc.
__global__ __launch_bounds__(256) void gather1_kernel(const int* __restrict__ row_ptr,
                                                      const int* __restrict__ esrc,
                                                      const unsigned short* __restrict__ xh,
                                                      const float* __restrict__ src_norm,
                                                      unsigned short* __restrict__ aggb) {
    int node = (blockIdx.x * blockDim.x + threadIdx.x) >> 6;
    int lane = threadIdx.x & 63;
    if (node >= NN) return;
    int beg = __builtin_amdgcn_readfirstlane(row_ptr[node]);
    int end = __builtin_amdgcn_readfirstlane(row_ptr[node + 1]);
    const int half = lane >> 5;
    const int l32  = lane & 31;
    float4 acc = make_float4(0.f, 0.f, 0.f, 0.f);
    int e = beg;
    for (; e + 16 <= end; e += 16) {
        int s0 = esrc[e + 0 + half];
        int s1 = esrc[e + 2 + half];
        int s2 = esrc[e + 4 + half];
        int s3 = esrc[e + 6 + half];
        int s4 = esrc[e + 8 + half];
        int s5 = esrc[e + 10 + half];
        int s6 = esrc[e + 12 + half];
        int s7 = esrc[e + 14 + half];
        float n0 = src_norm[s0], n1 = src_norm[s1], n2 = src_norm[s2], n3 = src_norm[s3];
        float n4 = src_norm[s4], n5 = src_norm[s5], n6 = src_norm[s6], n7 = src_norm[s7];
        uint2 u0 = ((const uint2*)(xh + (size_t)s0 * INF))[l32];
        uint2 u1 = ((const uint2*)(xh + (size_t)s1 * INF))[l32];
        uint2 u2 = ((const uint2*)(xh + (size_t)s2 * INF))[l32];
        uint2 u3 = ((const uint2*)(xh + (size_t)s3 * INF))[l32];
        uint2 u4 = ((const uint2*)(xh + (size_t)s4 * INF))[l32];
        uint2 u5 = ((const uint2*)(xh + (size_t)s5 * INF))[l32];
        uint2 u6 = ((const uint2*)(xh + (size_t)s6 * INF))[l32];
        uint2 u7 = ((const uint2*)(xh + (size_t)s7 * INF))[l32];
        acc.x += bflo(u0.x) * n0; acc.y += bfhi(u0.x) * n0; acc.z += bflo(u0.y) * n0; acc.w += bfhi(u0.y) * n0;
        acc.x += bflo(u1.x) * n1; acc.y += bfhi(u1.x) * n1; acc.z += bflo(u1.y) * n1; acc.w += bfhi(u1.y) * n1;
        acc.x += bflo(u2.x) * n2; acc.y += bfhi(u2.x) * n2; acc.z += bflo(u2.y) * n2; acc.w += bfhi(u2.y) * n2;
        acc.x += bflo(u3.x) * n3; acc.y += bfhi(u3.x) * n3; acc.z += bflo(u3.y) * n3; acc.w += bfhi(u3.y) * n3;
        acc.x += bflo(u4.x) * n4; acc.y += bfhi(u4.x) * n4; acc.z += bflo(u4.y) * n4; acc.w += bfhi(u4.y) * n4;
        acc.x += bflo(u5.x) * n5; acc.y += bfhi(u5.x) * n5; acc.z += bflo(u5.y) * n5; acc.w += bfhi(u5.y) * n5;
        acc.x += bflo(u6.x) * n6; acc.y += bfhi(u6.x) * n6; acc.z += bflo(u6.y) * n6; acc.w += bfhi(u6.y) * n6;
        acc.x += bflo(u7.x) * n7; acc.y += bfhi(u7.x) * n7; acc.z += bflo(u7.y) * n7; acc.w += bfhi(u7.y) * n7;
    }
    for (; e + 2 <= end; e += 2) {
        int s0 = esrc[e + half];
        float n0 = src_norm[s0];
        uint2 u0 = ((const uint2*)(xh + (size_t)s0 * INF))[l32];
        acc.x += bflo(u0.x) * n0; acc.y += bfhi(u0.x) * n0; acc.z += bflo(u0.y) * n0; acc.w += bfhi(u0.y) * n0;
    }
    if (e < end && half == 0) {
        int s0 = esrc[e];
        float n0 = src_norm[s0];
        uint2 u0 = ((const uint2*)(xh + (size_t)s0 * INF))[l32];
        acc.x += bflo(u0.x) * n0; acc.y += bfhi(u0.x) * n0; acc.z += bflo(u0.y) * n0; acc.w += bfhi(u0.y) * n0;
    }
    acc.x += __shfl_down(acc.x, 32);
    acc.y += __shfl_down(acc.y, 32);
    acc.z += __shfl_down(acc.z, 32);
    acc.w += __shfl_down(acc.w, 32);
    if (half == 0) {
        uint2 o;
        o.x = pack2(acc.x, acc.y);
        o.y = pack2(acc.z, acc.w);
        ((uint2*)(aggb + (size_t)node * INF))[l32] = o;
    }
}

// Fused GEMM1+GEMM2 via MFMA 16x16x32 bf16. 64 rows/block, 4 waves, wave-private rows.
// h = relu(dstn*(agg@W1) + b1) into LDS (bf16), then out = (h@W2)*srcn -> hwb.
__global__ __launch_bounds__(256) void gemm12_kernel(const unsigned short* __restrict__ aggb,
                                                     const unsigned short* __restrict__ w1t,
                                                     const unsigned short* __restrict__ w2t,
                                                     const float* __restrict__ b1,
                                                     const float* __restrict__ dstn,
                                                     const float* __restrict__ srcn,
                                                     unsigned short* __restrict__ hwb) {
    __shared__ unsigned short At[64 * 128];    // 16 KB: agg tile, then h tile
    __shared__ unsigned short W1l[128 * 128];  // 32 KB
    __shared__ unsigned short W2l[48 * 128];   // 12 KB
    __shared__ float dn[64], sn[64], b1l[128];
    const int tid = threadIdx.x;
    const int r0 = blockIdx.x * 64;

    {   // stage weights (uint4 = 8 bf16)
        const uint4* g1 = (const uint4*)w1t;
        uint4* s1 = (uint4*)W1l;
        for (int i = tid; i < 2048; i += 256) s1[i] = g1[i];
        const uint4* g2 = (const uint4*)w2t;
        uint4* s2 = (uint4*)W2l;
        for (int i = tid; i < 768; i += 256) s2[i] = g2[i];
    }
    {   // stage agg tile (zero-pad rows >= NN)
        const uint4* g = (const uint4*)(aggb + (size_t)r0 * 128);
        uint4* s = (uint4*)At;
        for (int i = tid; i < 1024; i += 256) {
            int row = i >> 4;
            uint4 v = make_uint4(0, 0, 0, 0);
            if (r0 + row < NN) v = g[i];
            s[i] = v;
        }
    }
    if (tid < 64) {
        int r = r0 + tid;
        dn[tid] = (r < NN) ? dstn[r] : 0.f;
        sn[tid] = (r < NN) ? srcn[r] : 0.f;
    }
    if (tid >= 64 && tid < 192) b1l[tid - 64] = b1[tid - 64];
    __syncthreads();

    const int wv    = tid >> 6;
    const int lane  = tid & 63;
    const int lrow  = lane & 15;
    const int lquad = lane >> 4;

    short8 afrag[4];
#pragma unroll
    for (int ks = 0; ks < 4; ++ks)
        afrag[ks] = *(const short8*)&At[(wv * 16 + lrow) * 128 + ks * 32 + lquad * 8];
    float hreg[8][4];
#pragma unroll
    for (int nt = 0; nt < 8; ++nt) {
        f32x4 acc = {0.f, 0.f, 0.f, 0.f};
#pragma unroll
        for (int ks = 0; ks < 4; ++ks) {
            short8 bfr = *(const short8*)&W1l[(nt * 16 + lrow) * 128 + ks * 32 + lquad * 8];
            acc = __builtin_amdgcn_mfma_f32_16x16x32_bf16(afrag[ks], bfr, acc, 0, 0, 0);
        }
#pragma unroll
        for (int i = 0; i < 4; ++i) hreg[nt][i] = acc[i];
    }
#pragma unroll
    for (int nt = 0; nt < 8; ++nt) {
        int col = nt * 16 + lrow;
        float bb = b1l[col];
#pragma unroll
        for (int i = 0; i < 4; ++i) {
            int row = wv * 16 + lquad * 4 + i;
            At[row * 128 + col] = f2bf(fmaxf(hreg[nt][i] * dn[row] + bb, 0.f));
        }
    }
    __syncthreads();

#pragma unroll
    for (int ks = 0; ks < 4; ++ks)
        afrag[ks] = *(const short8*)&At[(wv * 16 + lrow) * 128 + ks * 32 + lquad * 8];
#pragma unroll
    for (int nt = 0; nt < 3; ++nt) {
        f32x4 acc = {0.f, 0.f, 0.f, 0.f};
#pragma unroll
        for (int ks = 0; ks < 4; ++ks) {
            short8 bfr = *(const short8*)&W2l[(nt * 16 + lrow) * 128 + ks * 32 + lquad * 8];
            acc = __builtin_amdgcn_mfma_f32_16x16x32_bf16(afrag[ks], bfr, acc, 0, 0, 0);
        }
        int col = nt * 16 + lrow;
        if (col < NC) {
#pragma unroll
            for (int i = 0; i < 4; ++i) {
                int row = wv * 16 + lquad * 4 + i;
                int grow = r0 + row;
                if (grow < NN)
                    hwb[(size_t)grow * NC + col] = f2bf(acc[i] * sn[row]);
            }
        }
    }
}

// one wave per node. lane = g*10+j (g<6, j<10): 6 edges per step, each edge's
// 80 B row read by 10 lanes as uint2 (4 bf16). fp32 acc; 5x4 shfl reduce into
// lanes 0..9, which store float4 with fused *dstn + b2.
__global__ __launch_bounds__(256) void gather2_kernel(const int* __restrict__ row_ptr,
                                                      const int* __restrict__ esrc,
                                                      const unsigned short* __restrict__ hwb,
                                                      const float* __restrict__ dst_norm,
                                                      const float* __restrict__ b2,
                                                      float* __restrict__ out) {
    int node = (blockIdx.x * blockDim.x + threadIdx.x) >> 6;
    int lane = threadIdx.x & 63;
    if (node >= NN) return;
    int beg = __builtin_amdgcn_readfirstlane(row_ptr[node]);
    int end = __builtin_amdgcn_readfirstlane(row_ptr[node + 1]);
    const int g = lane / 10;          // edge slot 0..5 (g==6: lanes 60-63 idle)
    const int j = lane - g * 10;      // uint2 index within 80 B row
    float4 acc = make_float4(0.f, 0.f, 0.f, 0.f);
    int e = beg;
    for (; e + 6 <= end; e += 6) {
        if (g < 6) {
            int s = esrc[e + g];
            uint2 u = ((const uint2*)(hwb + (size_t)s * NC))[j];
            acc.x += bflo(u.x); acc.y += bfhi(u.x);
            acc.z += bflo(u.y); acc.w += bfhi(u.y);
        }
    }
    if (g < 6 && e + g < end) {
        int s = esrc[e + g];
        uint2 u = ((const uint2*)(hwb + (size_t)s * NC))[j];
        acc.x += bflo(u.x); acc.y += bfhi(u.x);
        acc.z += bflo(u.y); acc.w += bfhi(u.y);
    }
    // reduce groups g=1..5 into g=0 (acc stays unmodified; tot accumulates)
    float4 tot = acc;
#pragma unroll
    for (int k = 1; k < 6; ++k) {
        tot.x += __shfl(acc.x, j + 10 * k);
        tot.y += __shfl(acc.y, j + 10 * k);
        tot.z += __shfl(acc.z, j + 10 * k);
        tot.w += __shfl(acc.w, j + 10 * k);
    }
    if (lane < 10) {
        float dnv = dst_norm[node];
        float4 bb = ((const float4*)b2)[j];
        float4 o;
        o.x = tot.x * dnv + bb.x;
        o.y = tot.y * dnv + bb.y;
        o.z = tot.z * dnv + bb.z;
        o.w = tot.w * dnv + bb.w;
        ((float4*)(out + (size_t)node * NC))[j] = o;
    }
}

extern "C" void kernel_launch(void* const* d_in, const int* in_sizes, int n_in,
                              void* d_out, int out_size, void* d_ws, size_t ws_size,
                              hipStream_t stream) {
    const float* x   = (const float*)d_in[0];
    const float* W1  = (const float*)d_in[1];
    const float* b1  = (const float*)d_in[2];
    const float* W2  = (const float*)d_in[3];
    const float* b2  = (const float*)d_in[4];
    const int*   src = (const int*)d_in[5];
    const int*   dst = (const int*)d_in[6];
    float* out = (float*)d_out;

    // workspace (4B units):
    // deg_out[NN] | bucket_cnt[256] | cursor[256] | row_ptr[NN+1] | dstn[NN] |
    // esrc[NE] | pad | aggb[NN*64] | xh[NN*64] | w1t[8192] | w2t[3072]
    // hwb (bf16 NN*40) ALIASES xh (xh dead after gather1, hwb written by gemm12 after).
    unsigned int* deg_out    = (unsigned int*)d_ws;
    unsigned int* bucket_cnt = deg_out + NN;
    int* cursor  = (int*)(bucket_cnt + 256);
    int* row_ptr = cursor + 256;
    float* dstn  = (float*)(row_ptr + NN + 1);
    int* esrc    = (int*)(dstn + NN);
    size_t ofs = (size_t)NN + 512 + (NN + 1) + NN + NE;
    ofs = (ofs + 3) & ~(size_t)3;                 // 16B align
    unsigned short* aggb = (unsigned short*)((float*)d_ws + ofs);
    unsigned short* xh   = aggb + (size_t)NN * INF;
    unsigned short* w1t  = xh + (size_t)NN * INF;
    unsigned short* w2t  = w1t + 128 * 128;
    unsigned short* hwb  = xh;                    // alias — see lifetime note above

    // eparts scratch lives in d_out (6.4 MB of 16 MB) — dead before gather2 writes
    int* eparts = (int*)d_out;

    hipMemsetAsync(deg_out, 0, ((size_t)NN + 512) * sizeof(int), stream);

    histconv_kernel<<<HB + 6252, 256, 0, stream>>>(src, dst, deg_out, bucket_cnt,
                                                   x, W1, W2, xh, w1t, w2t);
    partition_kernel<<<PBLK, 256, 0, stream>>>(src, dst, bucket_cnt, cursor, eparts);
    pass2_kernel<<<NBK, 512, 0, stream>>>(eparts, bucket_cnt, row_ptr, esrc, deg_out, dstn);
    // src_norm = (float*)deg_out, dst_norm = dstn (written by pass2)
    gather1_kernel<<<(NN * 64 + 255) / 256, 256, 0, stream>>>(row_ptr, esrc, xh,
                                                              (const float*)deg_out, aggb);
    gemm12_kernel<<<(NN + 63) / 64, 256, 0, stream>>>(aggb, w1t, w2t, b1, dstn,
                                                      (const float*)deg_out, hwb);
    gather2_kernel<<<(NN * 64 + 255) / 256, 256, 0, stream>>>(row_ptr, esrc, hwb,
                                                              dstn, b2, out);
}

// Round 9
// 340.653 us; speedup vs baseline: 5.8116x; 1.1124x over previous
//
#include <hip/hip_runtime.h>

// GCN: 2-layer GraphConv, N=100000, E=1600000, 128 -> 128 -> 40 (fp32).
// Round 9: src out-degree via dual counting-sort (no per-node global atomics at all).
//   memset(4KB) -> histconv (coarse src+dst bucket hists, LDS only; + x/W converts) ->
//   partition (dual LDS-staged: dst-records + src-records, coalesced dumps) ->
//   pass2 (dst CSR + src out-degree hist in LDS -> row_ptr, dstn, srcn, esrc) ->
//   gather1(bf16) -> gemm12(MFMA fused) -> gather2(fused epilogue)
constexpr int NN   = 100000;
constexpr int NE   = 1600000;
constexpr int INF  = 128;
constexpr int NC   = 40;

constexpr int BKSH = 9;                        // 512 nodes per coarse bucket
constexpr int NBK  = (NN + 511) / 512;         // 196 buckets
constexpr int EPB  = 4096;                     // edges per partition block
constexpr int PBLK = (NE + EPB - 1) / EPB;     // 391
constexpr int CAP  = 14336;                    // pass2 LDS esrc capacity (56 KB)
constexpr int HB   = 391;                      // hist blocks in merged kernel

typedef __attribute__((ext_vector_type(8))) short short8;
typedef __attribute__((ext_vector_type(4))) float f32x4;

__device__ __forceinline__ float bflo(unsigned int u) { return __uint_as_float(u << 16); }
__device__ __forceinline__ float bfhi(unsigned int u) { return __uint_as_float(u & 0xffff0000u); }
__device__ __forceinline__ unsigned short f2bf(float f) {          // RNE
    unsigned int u = __float_as_uint(f);
    return (unsigned short)((u + 0x7fffu + ((u >> 16) & 1u)) >> 16);
}
__device__ __forceinline__ unsigned int pack2(float a, float b) {
    return (unsigned int)f2bf(a) | ((unsigned int)f2bf(b) << 16);
}

// blocks 0..HB-1: coarse dst-bucket AND src-bucket histograms (LDS aggregated).
// blocks HB..HB+6249: x (fp32) -> xh (bf16). +2 blocks: W1/W2 transpose->bf16.
__global__ __launch_bounds__(256) void histconv_kernel(const int* __restrict__ src,
                                                       const int* __restrict__ dst,
                                                       unsigned int* __restrict__ bcntD,
                                                       unsigned int* __restrict__ bcntS,
                                                       const float* __restrict__ x,
                                                       const float* __restrict__ W1,
                                                       const float* __restrict__ W2,
                                                       unsigned short* __restrict__ xh,
                                                       unsigned short* __restrict__ w1t,
                                                       unsigned short* __restrict__ w2t) {
    const int b = blockIdx.x;
    const int tid = threadIdx.x;
    if (b < HB) {
        __shared__ unsigned int hcD[NBK];
        __shared__ unsigned int hcS[NBK];
        for (int i = tid; i < NBK; i += 256) { hcD[i] = 0u; hcS[i] = 0u; }
        __syncthreads();
        int gid = b * 256 + tid;
        int stride = HB * 256;
        for (int e = gid; e < NE; e += stride) {
            atomicAdd(&hcD[dst[e] >> BKSH], 1u);
            atomicAdd(&hcS[src[e] >> BKSH], 1u);
        }
        __syncthreads();
        for (int i = tid; i < NBK; i += 256) {
            if (hcD[i]) atomicAdd(&bcntD[i], hcD[i]);
            if (hcS[i]) atomicAdd(&bcntS[i], hcS[i]);
        }
    } else if (b < HB + 6250) {
        int j = (b - HB) * 256 + tid;                // uint4 index, N*128/8 = 1.6M
        float4 v0 = ((const float4*)x)[2 * j];
        float4 v1 = ((const float4*)x)[2 * j + 1];
        uint4 o;
        o.x = pack2(v0.x, v0.y);
        o.y = pack2(v0.z, v0.w);
        o.z = pack2(v1.x, v1.y);
        o.w = pack2(v1.z, v1.w);
        ((uint4*)xh)[j] = o;
    } else if (b == HB + 6250) {
        for (int i = tid; i < 128 * 128; i += 256) {
            int k = i >> 7, n = i & 127;
            w1t[n * 128 + k] = f2bf(W1[i]);
        }
    } else {
        for (int i = tid; i < 48 * 128; i += 256) {
            int n = i >> 7, k = i & 127;
            w2t[i] = f2bf((n < NC) ? W2[k * NC + n] : 0.f);
        }
    }
}

// dual partition: dst-records (src | dst_local<<17) into epartsD, src-records
// (ushort src_local) into epartsS. Both LDS-staged -> coalesced run dumps.
__global__ __launch_bounds__(256) void partition_kernel(const int* __restrict__ src,
                                                        const int* __restrict__ dst,
                                                        const unsigned int* __restrict__ bcntD,
                                                        const unsigned int* __restrict__ bcntS,
                                                        int* __restrict__ curD_g,
                                                        int* __restrict__ curS_g,
                                                        int* __restrict__ epartsD,
                                                        unsigned short* __restrict__ epartsS) {
    __shared__ int sc[256];
    __shared__ int cntD[NBK], gadjD[NBK], curD[NBK];
    __shared__ int cntS[NBK], gadjS[NBK], curS[NBK];
    __shared__ int baselD[NBK], baselS[NBK];
    __shared__ int stageD[EPB];
    __shared__ unsigned short stageS[EPB];
    __shared__ unsigned char bidD[EPB];
    __shared__ unsigned char bidS[EPB];
    const int tid = threadIdx.x;
    const int e0 = blockIdx.x * EPB;
    const int total = min(EPB, NE - e0);

    // self-scan of global bucket counts -> base offsets (dst then src)
    {
        int v = (tid < NBK) ? (int)bcntD[tid] : 0;
        sc[tid] = v;
        __syncthreads();
        for (int off = 1; off < 256; off <<= 1) {
            int t = (tid >= off) ? sc[tid - off] : 0;
            __syncthreads();
            sc[tid] += t;
            __syncthreads();
        }
        if (tid < NBK) baselD[tid] = sc[tid] - v;
        __syncthreads();
        v = (tid < NBK) ? (int)bcntS[tid] : 0;
        sc[tid] = v;
        __syncthreads();
        for (int off = 1; off < 256; off <<= 1) {
            int t = (tid >= off) ? sc[tid - off] : 0;
            __syncthreads();
            sc[tid] += t;
            __syncthreads();
        }
        if (tid < NBK) baselS[tid] = sc[tid] - v;
    }
    for (int i = tid; i < NBK; i += 256) { cntD[i] = 0; cntS[i] = 0; }
    __syncthreads();
    // phase A: count per bucket (both keys)
    for (int i = tid; i < total; i += 256) {
        atomicAdd(&cntD[dst[e0 + i] >> BKSH], 1);
        atomicAdd(&cntS[src[e0 + i] >> BKSH], 1);
    }
    __syncthreads();
    // exclusive scans of cntD, cntS; reserve global ranges
    {
        int v = (tid < NBK) ? cntD[tid] : 0;
        sc[tid] = v;
        __syncthreads();
        for (int off = 1; off < 256; off <<= 1) {
            int t = (tid >= off) ? sc[tid - off] : 0;
            __syncthreads();
            sc[tid] += t;
            __syncthreads();
        }
        if (tid < NBK) {
            int excl = sc[tid] - v;
            curD[tid] = excl;
            int g = (v > 0) ? atomicAdd(&curD_g[tid], v) : 0;   // zero-based
            gadjD[tid] = baselD[tid] + g - excl;
        }
        __syncthreads();
        v = (tid < NBK) ? cntS[tid] : 0;
        sc[tid] = v;
        __syncthreads();
        for (int off = 1; off < 256; off <<= 1) {
            int t = (tid >= off) ? sc[tid - off] : 0;
            __syncthreads();
            sc[tid] += t;
            __syncthreads();
        }
        if (tid < NBK) {
            int excl = sc[tid] - v;
            curS[tid] = excl;
            int g = (v > 0) ? atomicAdd(&curS_g[tid], v) : 0;
            gadjS[tid] = baselS[tid] + g - excl;
        }
    }
    __syncthreads();
    // phase B: re-read edges, stage grouped by bucket (both keys)
    for (int i = tid; i < total; i += 256) {
        int s = src[e0 + i];
        int d = dst[e0 + i];
        int bD = d >> BKSH;
        int offD = atomicAdd(&curD[bD], 1);
        stageD[offD] = s | ((d - (bD << BKSH)) << 17);
        bidD[offD] = (unsigned char)bD;
        int bS = s >> BKSH;
        int offS = atomicAdd(&curS[bS], 1);
        stageS[offS] = (unsigned short)(s - (bS << BKSH));
        bidS[offS] = (unsigned char)bS;
    }
    __syncthreads();
    // dumps: consecutive j within a bucket-run -> consecutive global addresses
    for (int j = tid; j < total; j += 256) {
        int b = bidD[j];
        epartsD[gadjD[b] + j] = stageD[j];
    }
    for (int j = tid; j < total; j += 256) {
        int b = bidS[j];
        epartsS[gadjS[b] + j] = stageS[j];
    }
}

// per-bucket: dst CSR (hist+scan+LDS scatter -> row_ptr, dstn, esrc) AND
// src out-degree hist -> srcn. All histograms in LDS.
__global__ __launch_bounds__(512) void pass2_kernel(const int* __restrict__ epartsD,
                                                    const unsigned short* __restrict__ epartsS,
                                                    const unsigned int* __restrict__ bcntD,
                                                    const unsigned int* __restrict__ bcntS,
                                                    int* __restrict__ row_ptr,
                                                    int* __restrict__ esrc,
                                                    float* __restrict__ srcn,
                                                    float* __restrict__ dstn) {
    __shared__ int hist[512];
    __shared__ int cur[512];
    __shared__ int histS[512];
    __shared__ int lesrc[CAP];
    __shared__ int base_s, cnt_s, baseS_s, cntS_s;
    const int tid = threadIdx.x;
    const int b = blockIdx.x;

    // self-scans of bucket counts -> this bucket's base/cnt (dst, then src)
    {
        int v = (tid < NBK) ? (int)bcntD[tid] : 0;
        hist[tid] = v;
        __syncthreads();
        for (int off = 1; off < 512; off <<= 1) {
            int t = (tid >= off) ? hist[tid - off] : 0;
            __syncthreads();
            hist[tid] += t;
            __syncthreads();
        }
        if (tid == b) { base_s = hist[b] - v; cnt_s = v; }
        __syncthreads();
        v = (tid < NBK) ? (int)bcntS[tid] : 0;
        hist[tid] = v;
        __syncthreads();
        for (int off = 1; off < 512; off <<= 1) {
            int t = (tid >= off) ? hist[tid - off] : 0;
            __syncthreads();
            hist[tid] += t;
            __syncthreads();
        }
        if (tid == b) { baseS_s = hist[b] - v; cntS_s = v; }
        __syncthreads();
    }
    const int base = base_s;
    const int cnt = cnt_s;
    const int baseS = baseS_s;
    const int cntS = cntS_s;
    const int n0 = b << BKSH;
    const int nloc = min(512, NN - n0);

    hist[tid] = 0;
    histS[tid] = 0;
    __syncthreads();
    for (int j = tid; j < cnt; j += 512)
        atomicAdd(&hist[epartsD[base + j] >> 17], 1);
    for (int j = tid; j < cntS; j += 512)
        atomicAdd(&histS[(int)epartsS[baseS + j]], 1);
    __syncthreads();
    int myc = hist[tid];
    int mycS = histS[tid];
    for (int off = 1; off < 512; off <<= 1) {
        int t = (tid >= off) ? hist[tid - off] : 0;
        __syncthreads();
        hist[tid] += t;
        __syncthreads();
    }
    int excl = hist[tid] - myc;
    cur[tid] = excl;
    if (tid < nloc) {
        int g = n0 + tid;
        row_ptr[g] = base + excl;
        dstn[g] = rsqrtf(fmaxf((float)myc, 1.0f));    // dst_norm (in-degree)
        srcn[g] = rsqrtf(fmaxf((float)mycS, 1.0f));   // src_norm (out-degree)
    }
    if (b == NBK - 1 && tid == 0) row_ptr[NN] = NE;
    __syncthreads();
    if (cnt <= CAP) {
        for (int j = tid; j < cnt; j += 512) {
            int rec = epartsD[base + j];
            int pos = atomicAdd(&cur[rec >> 17], 1);
            lesrc[pos] = rec & 0x1FFFF;
        }
        __syncthreads();
        for (int j = tid; j < cnt; j += 512) esrc[base + j] = lesrc[j];
    } else {
        for (int j = tid; j < cnt; j += 512) {
            int rec = epartsD[base + j];
            int pos = atomicAdd(&cur[rec >> 17], 1);
            esrc[base + pos] = rec & 0x1FFFF;
        }
    }
}

// one wave per node: aggb[node] = bf16( sum x_bf16[esrc[e]] * src_norm[esrc[e]] )
// half-waves over edge pairs; uint2 (4 bf16)/lane; 16 edges in flight; fp32 acc.
__global__ __launch_bounds__(256) void gather1_kernel(const int* __restrict__ row_ptr,
                                                      const int* __restrict__ esrc,
                                                      const unsigned short* __restrict__ xh,
                                                      const float* __restrict__ src_norm,
                                                      unsigned short* __restrict__ aggb) {
    int node = (blockIdx.x * blockDim.x + threadIdx.x) >> 6;
    int lane = threadIdx.x & 63;
    if (node >= NN) return;
    int beg = __builtin_amdgcn_readfirstlane(row_ptr[node]);
    int end = __builtin_amdgcn_readfirstlane(row_ptr[node + 1]);
    const int half = lane >> 5;
    const int l32  = lane & 31;
    float4 acc = make_float4(0.f, 0.f, 0.f, 0.f);
    int e = beg;
    for (; e + 16 <= end; e += 16) {
        int s0 = esrc[e + 0 + half];
        int s1 = esrc[e + 2 + half];
        int s2 = esrc[e + 4 + half];
        int s3 = esrc[e + 6 + half];
        int s4 = esrc[e + 8 + half];
        int s5 = esrc[e + 10 + half];
        int s6 = esrc[e + 12 + half];
        int s7 = esrc[e + 14 + half];
        float n0 = src_norm[s0], n1 = src_norm[s1], n2 = src_norm[s2], n3 = src_norm[s3];
        float n4 = src_norm[s4], n5 = src_norm[s5], n6 = src_norm[s6], n7 = src_norm[s7];
        uint2 u0 = ((const uint2*)(xh + (size_t)s0 * INF))[l32];
        uint2 u1 = ((const uint2*)(xh + (size_t)s1 * INF))[l32];
        uint2 u2 = ((const uint2*)(xh + (size_t)s2 * INF))[l32];
        uint2 u3 = ((const uint2*)(xh + (size_t)s3 * INF))[l32];
        uint2 u4 = ((const uint2*)(xh + (size_t)s4 * INF))[l32];
        uint2 u5 = ((const uint2*)(xh + (size_t)s5 * INF))[l32];
        uint2 u6 = ((const uint2*)(xh + (size_t)s6 * INF))[l32];
        uint2 u7 = ((const uint2*)(xh + (size_t)s7 * INF))[l32];
        acc.x += bflo(u0.x) * n0; acc.y += bfhi(u0.x) * n0; acc.z += bflo(u0.y) * n0; acc.w += bfhi(u0.y) * n0;
        acc.x += bflo(u1.x) * n1; acc.y += bfhi(u1.x) * n1; acc.z += bflo(u1.y) * n1; acc.w += bfhi(u1.y) * n1;
        acc.x += bflo(u2.x) * n2; acc.y += bfhi(u2.x) * n2; acc.z += bflo(u2.y) * n2; acc.w += bfhi(u2.y) * n2;
        acc.x += bflo(u3.x) * n3; acc.y += bfhi(u3.x) * n3; acc.z += bflo(u3.y) * n3; acc.w += bfhi(u3.y) * n3;
        acc.x += bflo(u4.x) * n4; acc.y += bfhi(u4.x) * n4; acc.z += bflo(u4.y) * n4; acc.w += bfhi(u4.y) * n4;
        acc.x += bflo(u5.x) * n5; acc.y += bfhi(u5.x) * n5; acc.z += bflo(u5.y) * n5; acc.w += bfhi(u5.y) * n5;
        acc.x += bflo(u6.x) * n6; acc.y += bfhi(u6.x) * n6; acc.z += bflo(u6.y) * n6; acc.w += bfhi(u6.y) * n6;
        acc.x += bflo(u7.x) * n7; acc.y += bfhi(u7.x) * n7; acc.z += bflo(u7.y) * n7; acc.w += bfhi(u7.y) * n7;
    }
    for (; e + 2 <= end; e += 2) {
        int s0 = esrc[e + half];
        float n0 = src_norm[s0];
        uint2 u0 = ((const uint2*)(xh + (size_t)s0 * INF))[l32];
        acc.x += bflo(u0.x) * n0; acc.y += bfhi(u0.x) * n0; acc.z += bflo(u0.y) * n0; acc.w += bfhi(u0.y) * n0;
    }
    if (e < end && half == 0) {
        int s0 = esrc[e];
        float n0 = src_norm[s0];
        uint2 u0 = ((const uint2*)(xh + (size_t)s0 * INF))[l32];
        acc.x += bflo(u0.x) * n0; acc.y += bfhi(u0.x) * n0; acc.z += bflo(u0.y) * n0; acc.w += bfhi(u0.y) * n0;
    }
    acc.x += __shfl_down(acc.x, 32);
    acc.y += __shfl_down(acc.y, 32);
    acc.z += __shfl_down(acc.z, 32);
    acc.w += __shfl_down(acc.w, 32);
    if (half == 0) {
        uint2 o;
        o.x = pack2(acc.x, acc.y);
        o.y = pack2(acc.z, acc.w);
        ((uint2*)(aggb + (size_t)node * INF))[l32] = o;
    }
}

// Fused GEMM1+GEMM2 via MFMA 16x16x32 bf16. 64 rows/block, 4 waves, wave-private rows.
// h = relu(dstn*(agg@W1) + b1) into LDS (bf16), then out = (h@W2)*srcn -> hwb.
__global__ __launch_bounds__(256) void gemm12_kernel(const unsigned short* __restrict__ aggb,
                                                     const unsigned short* __restrict__ w1t,
                                                     const unsigned short* __restrict__ w2t,
                                                     const float* __restrict__ b1,
                                                     const float* __restrict__ dstn,
                                                     const float* __restrict__ srcn,
                                                     unsigned short* __restrict__ hwb) {
    __shared__ unsigned short At[64 * 128];    // 16 KB: agg tile, then h tile
    __shared__ unsigned short W1l[128 * 128];  // 32 KB
    __shared__ unsigned short W2l[48 * 128];   // 12 KB
    __shared__ float dn[64], sn[64], b1l[128];
    const int tid = threadIdx.x;
    const int r0 = blockIdx.x * 64;

    {   // stage weights (uint4 = 8 bf16)
        const uint4* g1 = (const uint4*)w1t;
        uint4* s1 = (uint4*)W1l;
        for (int i = tid; i < 2048; i += 256) s1[i] = g1[i];
        const uint4* g2 = (const uint4*)w2t;
        uint4* s2 = (uint4*)W2l;
        for (int i = tid; i < 768; i += 256) s2[i] = g2[i];
    }
    {   // stage agg tile (zero-pad rows >= NN)
        const uint4* g = (const uint4*)(aggb + (size_t)r0 * 128);
        uint4* s = (uint4*)At;
        for (int i = tid; i < 1024; i += 256) {
            int row = i >> 4;
            uint4 v = make_uint4(0, 0, 0, 0);
            if (r0 + row < NN) v = g[i];
            s[i] = v;
        }
    }
    if (tid < 64) {
        int r = r0 + tid;
        dn[tid] = (r < NN) ? dstn[r] : 0.f;
        sn[tid] = (r < NN) ? srcn[r] : 0.f;
    }
    if (tid >= 64 && tid < 192) b1l[tid - 64] = b1[tid - 64];
    __syncthreads();

    const int wv    = tid >> 6;
    const int lane  = tid & 63;
    const int lrow  = lane & 15;
    const int lquad = lane >> 4;

    short8 afrag[4];
#pragma unroll
    for (int ks = 0; ks < 4; ++ks)
        afrag[ks] = *(const short8*)&At[(wv * 16 + lrow) * 128 + ks * 32 + lquad * 8];
    float hreg[8][4];
#pragma unroll
    for (int nt = 0; nt < 8; ++nt) {
        f32x4 acc = {0.f, 0.f, 0.f, 0.f};
#pragma unroll
        for (int ks = 0; ks < 4; ++ks) {
            short8 bfr = *(const short8*)&W1l[(nt * 16 + lrow) * 128 + ks * 32 + lquad * 8];
            acc = __builtin_amdgcn_mfma_f32_16x16x32_bf16(afrag[ks], bfr, acc, 0, 0, 0);
        }
#pragma unroll
        for (int i = 0; i < 4; ++i) hreg[nt][i] = acc[i];
    }
#pragma unroll
    for (int nt = 0; nt < 8; ++nt) {
        int col = nt * 16 + lrow;
        float bb = b1l[col];
#pragma unroll
        for (int i = 0; i < 4; ++i) {
            int row = wv * 16 + lquad * 4 + i;
            At[row * 128 + col] = f2bf(fmaxf(hreg[nt][i] * dn[row] + bb, 0.f));
        }
    }
    __syncthreads();

#pragma unroll
    for (int ks = 0; ks < 4; ++ks)
        afrag[ks] = *(const short8*)&At[(wv * 16 + lrow) * 128 + ks * 32 + lquad * 8];
#pragma unroll
    for (int nt = 0; nt < 3; ++nt) {
        f32x4 acc = {0.f, 0.f, 0.f, 0.f};
#pragma unroll
        for (int ks = 0; ks < 4; ++ks) {
            short8 bfr = *(const short8*)&W2l[(nt * 16 + lrow) * 128 + ks * 32 + lquad * 8];
            acc = __builtin_amdgcn_mfma_f32_16x16x32_bf16(afrag[ks], bfr, acc, 0, 0, 0);
        }
        int col = nt * 16 + lrow;
        if (col < NC) {
#pragma unroll
            for (int i = 0; i < 4; ++i) {
                int row = wv * 16 + lquad * 4 + i;
                int grow = r0 + row;
                if (grow < NN)
                    hwb[(size_t)grow * NC + col] = f2bf(acc[i] * sn[row]);
            }
        }
    }
}

// one wave per node. lane = g*10+j (g<6, j<10): 6 edges per step, each edge's
// 80 B row read by 10 lanes as uint2 (4 bf16). fp32 acc; shfl reduce into
// lanes 0..9, which store float4 with fused *dstn + b2.
__global__ __launch_bounds__(256) void gather2_kernel(const int* __restrict__ row_ptr,
                                                      const int* __restrict__ esrc,
                                                      const unsigned short* __restrict__ hwb,
                                                      const float* __restrict__ dst_norm,
                                                      const float* __restrict__ b2,
                                                      float* __restrict__ out) {
    int node = (blockIdx.x * blockDim.x + threadIdx.x) >> 6;
    int lane = threadIdx.x & 63;
    if (node >= NN) return;
    int beg = __builtin_amdgcn_readfirstlane(row_ptr[node]);
    int end = __builtin_amdgcn_readfirstlane(row_ptr[node + 1]);
    const int g = lane / 10;          // edge slot 0..5 (g==6: lanes 60-63 idle)
    const int j = lane - g * 10;      // uint2 index within 80 B row
    float4 acc = make_float4(0.f, 0.f, 0.f, 0.f);
    int e = beg;
    for (; e + 6 <= end; e += 6) {
        if (g < 6) {
            int s = esrc[e + g];
            uint2 u = ((const uint2*)(hwb + (size_t)s * NC))[j];
            acc.x += bflo(u.x); acc.y += bfhi(u.x);
            acc.z += bflo(u.y); acc.w += bfhi(u.y);
        }
    }
    if (g < 6 && e + g < end) {
        int s = esrc[e + g];
        uint2 u = ((const uint2*)(hwb + (size_t)s * NC))[j];
        acc.x += bflo(u.x); acc.y += bfhi(u.x);
        acc.z += bflo(u.y); acc.w += bfhi(u.y);
    }
    float4 tot = acc;
#pragma unroll
    for (int k = 1; k < 6; ++k) {
        tot.x += __shfl(acc.x, j + 10 * k);
        tot.y += __shfl(acc.y, j + 10 * k);
        tot.z += __shfl(acc.z, j + 10 * k);
        tot.w += __shfl(acc.w, j + 10 * k);
    }
    if (lane < 10) {
        float dnv = dst_norm[node];
        float4 bb = ((const float4*)b2)[j];
        float4 o;
        o.x = tot.x * dnv + bb.x;
        o.y = tot.y * dnv + bb.y;
        o.z = tot.z * dnv + bb.z;
        o.w = tot.w * dnv + bb.w;
        ((float4*)(out + (size_t)node * NC))[j] = o;
    }
}

extern "C" void kernel_launch(void* const* d_in, const int* in_sizes, int n_in,
                              void* d_out, int out_size, void* d_ws, size_t ws_size,
                              hipStream_t stream) {
    const float* x   = (const float*)d_in[0];
    const float* W1  = (const float*)d_in[1];
    const float* b1  = (const float*)d_in[2];
    const float* W2  = (const float*)d_in[3];
    const float* b2  = (const float*)d_in[4];
    const int*   src = (const int*)d_in[5];
    const int*   dst = (const int*)d_in[6];
    float* out = (float*)d_out;

    // workspace (4B units):
    // srcn[NN] | bcntD[256] | bcntS[256] | curD[256] | curS[256] | row_ptr[NN+1] |
    // dstn[NN] | esrc[NE] | pad | aggb[NN*64] | xh[NN*64] | w1t[8192] | w2t[3072]
    // hwb (bf16 NN*40) ALIASES xh (xh dead after gather1, hwb written by gemm12 after).
    float* srcn = (float*)d_ws;
    unsigned int* bcntD = (unsigned int*)(srcn + NN);
    unsigned int* bcntS = bcntD + 256;
    int* curD = (int*)(bcntS + 256);
    int* curS = curD + 256;
    int* row_ptr = curS + 256;
    float* dstn  = (float*)(row_ptr + NN + 1);
    int* esrc    = (int*)(dstn + NN);
    size_t ofs = (size_t)NN + 1024 + (NN + 1) + NN + NE;
    ofs = (ofs + 3) & ~(size_t)3;                 // 16B align
    unsigned short* aggb = (unsigned short*)((float*)d_ws + ofs);
    unsigned short* xh   = aggb + (size_t)NN * INF;
    unsigned short* w1t  = xh + (size_t)NN * INF;
    unsigned short* w2t  = w1t + 128 * 128;
    unsigned short* hwb  = xh;                    // alias — see lifetime note above

    // edge-record scratch lives in d_out (9.6 MB of 16 MB) — dead before gather2 writes
    int* epartsD = (int*)d_out;                            // 6.4 MB
    unsigned short* epartsS = (unsigned short*)(epartsD + NE);  // 3.2 MB

    hipMemsetAsync(bcntD, 0, 1024 * sizeof(int), stream);  // bcntD|bcntS|curD|curS

    histconv_kernel<<<HB + 6252, 256, 0, stream>>>(src, dst, bcntD, bcntS,
                                                   x, W1, W2, xh, w1t, w2t);
    partition_kernel<<<PBLK, 256, 0, stream>>>(src, dst, bcntD, bcntS, curD, curS,
                                               epartsD, epartsS);
    pass2_kernel<<<NBK, 512, 0, stream>>>(epartsD, epartsS, bcntD, bcntS,
                                          row_ptr, esrc, srcn, dstn);
    gather1_kernel<<<(NN * 64 + 255) / 256, 256, 0, stream>>>(row_ptr, esrc, xh,
                                                              srcn, aggb);
    gemm12_kernel<<<(NN + 63) / 64, 256, 0, stream>>>(aggb, w1t, w2t, b1, dstn,
                                                      srcn, hwb);
    gather2_kernel<<<(NN * 64 + 255) / 256, 256, 0, stream>>>(row_ptr, esrc, hwb,
                                                              dstn, b2, out);
}